// Round 3
// baseline (5565.650 us; speedup 1.0000x reference)
//
#include <hip/hip_runtime.h>
#include <hip/hip_bf16.h>

// ForecastNetSimple: B=128, T=512, I=8, H=512, W=96
// Round 12: r10 skeleton (proven resident + absmax 0.0) with two sync fixes.
//  r11 post-mortem: sc0-only is SE scope (not XCD scope) -> flag updates can
//  stay invisible across SEs -> deadlock; and 256 blocks @1/CU has no
//  residency margin. Reverted both.
//  r10 counters: WRITE_SIZE 392 KB/step == h-plane buffer -> sc0 sc1 (SYSTEM
//  scope) stores write through the LLC to HBM, and consumers' first reads
//  come back from HBM (~900cyc/hop). Also each of 256 waves polled 32
//  distinct flag lines per iteration at system scope.
//  Fix 1: AGENT scope (sc1 only) for the whole h exchange -- the minimal
//  correct scope for cross-XCD visibility; lets the memory-side Infinity
//  Cache retain the traffic (hop ~900 -> ~450cyc).
//  Fix 2: per-(half,wave,step) release COUNTERS: each producer wave does one
//  agent-scope atomic_add after its vm_drain; consumers poll ONE broadcast
//  line until ==32 (was: 32-line gather per poll).
//  Data bytes, fragment layout, MFMA order, pd term order: bit-identical to
//  r10 -> absmax 0.0.
// 64 blocks x 256 threads, 1 block/CU; no __syncthreads in the 608-step loop.

typedef __attribute__((ext_vector_type(8))) short short8;
typedef __attribute__((ext_vector_type(4))) float f32x4;
typedef __attribute__((ext_vector_type(2))) unsigned int u32x2;

#define FS 32    // dwords between counter slots (128 B line isolation)
#define NSLOT 609  // step-publish values 1..608 (slot 0 unused)

// ---------- dtype helpers ----------
__device__ __forceinline__ float ldf(const void* p, size_t i, int isbf) {
  if (isbf) return __uint_as_float((unsigned)((const unsigned short*)p)[i] << 16);
  return ((const float*)p)[i];
}
__device__ __forceinline__ unsigned short f2bf(float x) {  // RNE
  unsigned u = __float_as_uint(x);
  return (unsigned short)((u + 0x7fff + ((u >> 16) & 1)) >> 16);
}
__device__ __forceinline__ unsigned short ldbf(const void* p, size_t i, int isbf) {
  if (isbf) return ((const unsigned short*)p)[i];
  return f2bf(((const float*)p)[i]);
}
__device__ __forceinline__ float bf2f(short s) {
  return __uint_as_float((unsigned)(unsigned short)s << 16);
}

// ---------- coherent access (agent scope: sc1) ----------
__device__ __forceinline__ void st_cx2(void* p, u32x2 v) {
  asm volatile("global_store_dwordx2 %0, %1, off sc1" :: "v"(p), "v"(v) : "memory");
}
__device__ __forceinline__ void vm_drain() {
  asm volatile("s_waitcnt vmcnt(0)" ::: "memory");
}

// ---- batch plane load: 48 x b128 agent-scope loads + internal drain
//      (contract-safe: no in-flight dest register visible to the compiler) ----
// layout: base = Hs + col*3072 + q*16 ; fragment i = kb*3+plane at byte i*64
__device__ __forceinline__ void load_planes48(const char* p, short8 hv[48]) {
  asm volatile(
    "global_load_dwordx4 %0, %48, off sc1\n\t"
    "global_load_dwordx4 %1, %48, off offset:64 sc1\n\t"
    "global_load_dwordx4 %2, %48, off offset:128 sc1\n\t"
    "global_load_dwordx4 %3, %48, off offset:192 sc1\n\t"
    "global_load_dwordx4 %4, %48, off offset:256 sc1\n\t"
    "global_load_dwordx4 %5, %48, off offset:320 sc1\n\t"
    "global_load_dwordx4 %6, %48, off offset:384 sc1\n\t"
    "global_load_dwordx4 %7, %48, off offset:448 sc1\n\t"
    "global_load_dwordx4 %8, %48, off offset:512 sc1\n\t"
    "global_load_dwordx4 %9, %48, off offset:576 sc1\n\t"
    "global_load_dwordx4 %10, %48, off offset:640 sc1\n\t"
    "global_load_dwordx4 %11, %48, off offset:704 sc1\n\t"
    "global_load_dwordx4 %12, %48, off offset:768 sc1\n\t"
    "global_load_dwordx4 %13, %48, off offset:832 sc1\n\t"
    "global_load_dwordx4 %14, %48, off offset:896 sc1\n\t"
    "global_load_dwordx4 %15, %48, off offset:960 sc1\n\t"
    "global_load_dwordx4 %16, %48, off offset:1024 sc1\n\t"
    "global_load_dwordx4 %17, %48, off offset:1088 sc1\n\t"
    "global_load_dwordx4 %18, %48, off offset:1152 sc1\n\t"
    "global_load_dwordx4 %19, %48, off offset:1216 sc1\n\t"
    "global_load_dwordx4 %20, %48, off offset:1280 sc1\n\t"
    "global_load_dwordx4 %21, %48, off offset:1344 sc1\n\t"
    "global_load_dwordx4 %22, %48, off offset:1408 sc1\n\t"
    "global_load_dwordx4 %23, %48, off offset:1472 sc1\n\t"
    "global_load_dwordx4 %24, %48, off offset:1536 sc1\n\t"
    "global_load_dwordx4 %25, %48, off offset:1600 sc1\n\t"
    "global_load_dwordx4 %26, %48, off offset:1664 sc1\n\t"
    "global_load_dwordx4 %27, %48, off offset:1728 sc1\n\t"
    "global_load_dwordx4 %28, %48, off offset:1792 sc1\n\t"
    "global_load_dwordx4 %29, %48, off offset:1856 sc1\n\t"
    "global_load_dwordx4 %30, %48, off offset:1920 sc1\n\t"
    "global_load_dwordx4 %31, %48, off offset:1984 sc1\n\t"
    "global_load_dwordx4 %32, %48, off offset:2048 sc1\n\t"
    "global_load_dwordx4 %33, %48, off offset:2112 sc1\n\t"
    "global_load_dwordx4 %34, %48, off offset:2176 sc1\n\t"
    "global_load_dwordx4 %35, %48, off offset:2240 sc1\n\t"
    "global_load_dwordx4 %36, %48, off offset:2304 sc1\n\t"
    "global_load_dwordx4 %37, %48, off offset:2368 sc1\n\t"
    "global_load_dwordx4 %38, %48, off offset:2432 sc1\n\t"
    "global_load_dwordx4 %39, %48, off offset:2496 sc1\n\t"
    "global_load_dwordx4 %40, %48, off offset:2560 sc1\n\t"
    "global_load_dwordx4 %41, %48, off offset:2624 sc1\n\t"
    "global_load_dwordx4 %42, %48, off offset:2688 sc1\n\t"
    "global_load_dwordx4 %43, %48, off offset:2752 sc1\n\t"
    "global_load_dwordx4 %44, %48, off offset:2816 sc1\n\t"
    "global_load_dwordx4 %45, %48, off offset:2880 sc1\n\t"
    "global_load_dwordx4 %46, %48, off offset:2944 sc1\n\t"
    "global_load_dwordx4 %47, %48, off offset:3008 sc1\n\t"
    "s_waitcnt vmcnt(0)"
    : "=&v"(hv[0]),  "=&v"(hv[1]),  "=&v"(hv[2]),  "=&v"(hv[3]),
      "=&v"(hv[4]),  "=&v"(hv[5]),  "=&v"(hv[6]),  "=&v"(hv[7]),
      "=&v"(hv[8]),  "=&v"(hv[9]),  "=&v"(hv[10]), "=&v"(hv[11]),
      "=&v"(hv[12]), "=&v"(hv[13]), "=&v"(hv[14]), "=&v"(hv[15]),
      "=&v"(hv[16]), "=&v"(hv[17]), "=&v"(hv[18]), "=&v"(hv[19]),
      "=&v"(hv[20]), "=&v"(hv[21]), "=&v"(hv[22]), "=&v"(hv[23]),
      "=&v"(hv[24]), "=&v"(hv[25]), "=&v"(hv[26]), "=&v"(hv[27]),
      "=&v"(hv[28]), "=&v"(hv[29]), "=&v"(hv[30]), "=&v"(hv[31]),
      "=&v"(hv[32]), "=&v"(hv[33]), "=&v"(hv[34]), "=&v"(hv[35]),
      "=&v"(hv[36]), "=&v"(hv[37]), "=&v"(hv[38]), "=&v"(hv[39]),
      "=&v"(hv[40]), "=&v"(hv[41]), "=&v"(hv[42]), "=&v"(hv[43]),
      "=&v"(hv[44]), "=&v"(hv[45]), "=&v"(hv[46]), "=&v"(hv[47])
    : "v"(p)
    : "memory");
}

// ---- producer: exact 3-way RNE split of 4 h values + agent-scope plane stores ----
// sb = Hs + col*3072 + (hb>>1)*192 + (hb&1)*32 + q*8 ; plane p at sb + p*64
__device__ __forceinline__ void split_store3(char* sb, const f32x4& hw) {
  unsigned pa[3][4];
#pragma unroll
  for (int r = 0; r < 4; ++r) {
    float x = hw[r];
    unsigned short a = f2bf(x);
    float r1 = x - bf2f((short)a);
    unsigned short bq = f2bf(r1);
    float r2 = r1 - bf2f((short)bq);
    pa[0][r] = a; pa[1][r] = bq; pa[2][r] = f2bf(r2);
  }
#pragma unroll
  for (int p3 = 0; p3 < 3; ++p3) {
    u32x2 v;
    v.x = pa[p3][0] | (pa[p3][1] << 16);
    v.y = pa[p3][2] | (pa[p3][3] << 16);
    st_cx2(sb + p3 * 64, v);
  }
}

// ---------- probe: bf16 vs fp32 input buffers ----------
__global__ void k_probe(const unsigned int* __restrict__ src_raw, int* __restrict__ flag) {
  __shared__ int cnt;
  if (threadIdx.x == 0) cnt = 0;
  __syncthreads();
  int c = 0;
  for (int i = threadIdx.x; i < 512; i += 256) {
    unsigned v = src_raw[i];
    float f = __uint_as_float((v & 0xffffu) << 16);
    float a = fabsf(f);
    if (a > 0.00390625f && a < 4.0f) c++;
  }
  atomicAdd(&cnt, c);
  __syncthreads();
  if (threadIdx.x == 0) *flag = (cnt > 256) ? 1 : 0;
}

// ---------- prepack A fragments ----------
__global__ void k_prep_frags(const void* __restrict__ Whh_e, const void* __restrict__ Whh_d,
                             const void* __restrict__ Wih_e,
                             short* __restrict__ AEnc, short* __restrict__ ADec,
                             const int* __restrict__ flag) {
  const int isbf = *flag;
  const int lane = threadIdx.x;            // 64 threads
  const int m = lane & 15, qd = lane >> 4;
  int bidp = blockIdx.x;
  if (bidp < 2176) {
    const int hb = bidp / 68, rem = bidp % 68, t = rem / 17, kb = rem % 17;
    const int row = t * 512 + hb * 16 + m;
    short v[8];
#pragma unroll
    for (int j = 0; j < 8; ++j) {
      if (kb < 16) {
        int k = kb * 32 + qd * 8 + j;
        v[j] = (short)ldbf(Whh_e, (size_t)row * 512 + k, isbf);
      } else {
        v[j] = (qd == 0) ? (short)ldbf(Wih_e, (size_t)row * 8 + j, isbf) : (short)0;
      }
    }
    short* dst = AEnc + ((size_t)bidp * 64 + lane) * 8;
#pragma unroll
    for (int j = 0; j < 8; ++j) dst[j] = v[j];
  } else {
    bidp -= 2176;
    const int hb = bidp / 64, rem = bidp % 64, t = rem / 16, kb = rem % 16;
    const int row = t * 512 + hb * 16 + m;
    short* dst = ADec + ((size_t)bidp * 64 + lane) * 8;
#pragma unroll
    for (int j = 0; j < 8; ++j) {
      int k = kb * 32 + qd * 8 + j;
      dst[j] = (short)ldbf(Whh_d, (size_t)row * 512 + k, isbf);
    }
  }
}

// ---------- prepack encoder x B-frags: XF[t][col][8] bf16 ----------
__global__ void k_prep_xf(const void* __restrict__ src, unsigned short* __restrict__ XF,
                          const int* __restrict__ flag) {
  const int isbf = *flag;
  int idx = blockIdx.x * 256 + threadIdx.x;        // < 524288
  int t = idx >> 10, rem = idx & 1023, col = rem >> 3, i = rem & 7;
  XF[idx] = ldbf(src, ((size_t)col * 512 + t) * 8 + i, isbf);
}

// ---------- small prep ----------
__global__ void k_prep_small(const void* __restrict__ bih_e, const void* __restrict__ bhh_e,
                             const void* __restrict__ bih_d, const void* __restrict__ bhh_d,
                             const void* __restrict__ Wih_d, const void* __restrict__ Wp,
                             const void* __restrict__ bp, const void* __restrict__ Wfc,
                             const void* __restrict__ bfc,
                             float* __restrict__ bE, float* __restrict__ uD,
                             float* __restrict__ bD, float* __restrict__ WfcF,
                             unsigned* __restrict__ arr, const int* __restrict__ flag) {
  const int isbf = *flag;
  const int b = blockIdx.x;
  if (b < 8) {
    int g = b * 256 + threadIdx.x;
    bE[g] = ldf(bih_e, g, isbf) + ldf(bhh_e, g, isbf);
    float u = 0.f, w0 = 0.f;
    for (int i = 0; i < 8; ++i) {
      float wv = ldf(Wih_d, (size_t)g * 8 + i, isbf);
      u  += wv * ldf(Wp, i, isbf);
      w0 += wv * ldf(bp, i, isbf);
    }
    uD[g] = u;
    bD[g] = ldf(bih_d, g, isbf) + ldf(bhh_d, g, isbf) + w0;
  } else if (b == 8) {
    for (int k = threadIdx.x; k < 513; k += 256)
      WfcF[k] = (k < 512) ? ldf(Wfc, k, isbf) : ldf(bfc, 0, isbf);
  } else {
    // zero 8 counter groups x 609 slots x FS dwords (blocks 9..15 cooperate)
    const int z = b - 9;                       // 0..6
    const int total = 8 * NSLOT * FS;          // 155904 dwords
    for (int i = z * 256 + threadIdx.x; i < total; i += 7 * 256) arr[i] = 0u;
  }
}

// ---------- math ----------
__device__ __forceinline__ float sigm(float x) { return 1.0f / (1.0f + __expf(-x)); }
__device__ __forceinline__ float tanh_(float x) {
  float ax = fabsf(x);
  float e = __expf(-2.0f * ax);
  float t = (1.0f - e) / (1.0f + e);
  return copysignf(t, x);
}

// ---------- main persistent recurrent kernel ----------
__global__ __launch_bounds__(256, 1) void k_rnn(
    const short* __restrict__ AEnc, const short* __restrict__ ADec,
    const unsigned short* __restrict__ XF,
    const float* __restrict__ bE, const float* __restrict__ uD,
    const float* __restrict__ bD, const float* __restrict__ WfcF,
    char* __restrict__ HsA, char* __restrict__ HsB,
    void* __restrict__ outp, const int* __restrict__ flag,
    unsigned* __restrict__ arr, const void* __restrict__ src) {
  const int bid  = (int)blockIdx.x;       // 64 blocks
  const int hb   = bid >> 1;              // produces h rows hb*16 .. +16
  const int half = bid & 1;
  const int tid  = (int)threadIdx.x;
  const int lane = tid & 63;
  const int w    = __builtin_amdgcn_readfirstlane(tid >> 6);  // col-tile 0..3
  const int n    = lane & 15, q = lane >> 4;
  const int col  = half * 64 + w * 16 + n;

  __shared__ short AeL[4 * 17 * 512];     // 69632 B
  __shared__ short AdL[4 * 16 * 512];     // 65536 B
  __shared__ float WfcL[520];
  __shared__ float bEL[64], uDL[64], bDL[64];

  // ---- one-time staging ----
  {
    const float4* s1 = (const float4*)(AEnc + (size_t)hb * 34816);
    float4* d1 = (float4*)AeL;
    for (int i = tid; i < 4352; i += 256) d1[i] = s1[i];
    const float4* s2 = (const float4*)(ADec + (size_t)hb * 32768);
    float4* d2 = (float4*)AdL;
    for (int i = tid; i < 4096; i += 256) d2[i] = s2[i];
    for (int k = tid; k < 513; k += 256) WfcL[k] = WfcF[k];
    if (tid < 64) {
      int t = tid >> 4, m = tid & 15;
      int g = t * 512 + hb * 16 + m;
      bEL[tid] = bE[g]; uDL[tid] = uD[g]; bDL[tid] = bD[g];
    }
  }
  const int isbf = *flag;
  // counter group for this (half, wave): producers = wave w of all 32 blocks
  // with this half; consumers = the same set. One slot per published step.
  unsigned* cbase = arr + (size_t)((half * 4 + w) * NSLOT) * FS;
  __syncthreads();   // LDS staging visible; last block-level sync

  const int lboff = col * 3072 + q * 16;                                  // consumer
  const int sboff = col * 3072 + (hb >> 1) * 192 + (hb & 1) * 32 + q * 8; // producer
  float cst[4] = {0.f, 0.f, 0.f, 0.f};

#define WAIT(nn)                                                              \
  do {                                                                        \
    const unsigned* _cp = cbase + (size_t)(nn) * FS;                          \
    while (__hip_atomic_load(_cp, __ATOMIC_RELAXED,                           \
                             __HIP_MEMORY_SCOPE_AGENT) < 32u)                 \
      __builtin_amdgcn_s_sleep(1);                                            \
    asm volatile("" ::: "memory");                                            \
  } while (0)

#define PUBLISH(nn)                                                           \
  do {                                                                        \
    if (lane == 0)                                                            \
      __hip_atomic_fetch_add(cbase + (size_t)(nn) * FS, 1u,                   \
                             __ATOMIC_RELAXED, __HIP_MEMORY_SCOPE_AGENT);     \
  } while (0)

  // ================= encoder: 512 steps =================
  for (int t = 0; t < 512; ++t) {
    char* wrW = (t & 1) ? HsA : HsB;             // h_{t+1} planes
    f32x4 acc[4] = {{0.f,0.f,0.f,0.f},{0.f,0.f,0.f,0.f},{0.f,0.f,0.f,0.f},{0.f,0.f,0.f,0.f}};
    short8 xb = short8{0,0,0,0,0,0,0,0};
    if (q == 0) xb = *(const short8*)((const short*)XF + ((size_t)t * 128 + col) * 8);

    if (t > 0) {
      const char* rdR = (t & 1) ? HsB : HsA;     // h_t planes
      WAIT(t);
      short8 hv[48];
      load_planes48(rdR + lboff, hv);            // 48 b128 loads + drain, in-asm
#pragma unroll
      for (int kb = 0; kb < 16; ++kb) {
#pragma unroll
        for (int tt = 0; tt < 4; ++tt) {
          short8 a = *(const short8*)(AeL + ((size_t)(tt * 17 + kb) * 64 + lane) * 8);
          acc[tt] = __builtin_amdgcn_mfma_f32_16x16x32_bf16(a, hv[kb * 3 + 0], acc[tt], 0, 0, 0);
          acc[tt] = __builtin_amdgcn_mfma_f32_16x16x32_bf16(a, hv[kb * 3 + 1], acc[tt], 0, 0, 0);
          acc[tt] = __builtin_amdgcn_mfma_f32_16x16x32_bf16(a, hv[kb * 3 + 2], acc[tt], 0, 0, 0);
        }
      }
    }
#pragma unroll
    for (int tt = 0; tt < 4; ++tt) {   // x-term K-block (last: r7 order)
      short8 a = *(const short8*)(AeL + ((size_t)(tt * 17 + 16) * 64 + lane) * 8);
      acc[tt] = __builtin_amdgcn_mfma_f32_16x16x32_bf16(a, xb, acc[tt], 0, 0, 0);
    }
    f32x4 hw;
#pragma unroll
    for (int r = 0; r < 4; ++r) {
      int m = q * 4 + r;
      float gi = acc[0][r] + bEL[m];
      float gf = acc[1][r] + bEL[16 + m];
      float gg = acc[2][r] + bEL[32 + m];
      float go = acc[3][r] + bEL[48 + m];
      cst[r] = sigm(gf) * cst[r] + sigm(gi) * tanh_(gg);
      hw[r] = sigm(go) * tanh_(cst[r]);
    }
    split_store3(wrW + sboff, hw);
    vm_drain();
    PUBLISH(t + 1);
  }

  // ================= decoder: 96 steps =================
  for (int d = 0; d < 96; ++d) {
    const int nn = 512 + d;
    const char* rdR = (nn & 1) ? HsB : HsA;
    char* wrW = (nn & 1) ? HsA : HsB;
    f32x4 acc[4] = {{0.f,0.f,0.f,0.f},{0.f,0.f,0.f,0.f},{0.f,0.f,0.f,0.f},{0.f,0.f,0.f,0.f}};
    float pd = 0.f;
    WAIT(nn);
    short8 hv[48];
    load_planes48(rdR + lboff, hv);
#pragma unroll
    for (int kb = 0; kb < 16; ++kb) {
#pragma unroll
      for (int j = 0; j < 8; ++j) {               // Wfc dot: same term order as r7/r10
        pd += WfcL[kb * 32 + q * 8 + j] *
              (bf2f(hv[kb * 3 + 0][j]) + bf2f(hv[kb * 3 + 1][j]) + bf2f(hv[kb * 3 + 2][j]));
      }
#pragma unroll
      for (int tt = 0; tt < 4; ++tt) {
        short8 a = *(const short8*)(AdL + ((size_t)(tt * 16 + kb) * 64 + lane) * 8);
        acc[tt] = __builtin_amdgcn_mfma_f32_16x16x32_bf16(a, hv[kb * 3 + 0], acc[tt], 0, 0, 0);
        acc[tt] = __builtin_amdgcn_mfma_f32_16x16x32_bf16(a, hv[kb * 3 + 1], acc[tt], 0, 0, 0);
        acc[tt] = __builtin_amdgcn_mfma_f32_16x16x32_bf16(a, hv[kb * 3 + 2], acc[tt], 0, 0, 0);
      }
    }
    pd += __shfl_xor(pd, 16);
    pd += __shfl_xor(pd, 32);
    float pr = sigm(pd + WfcL[512]);             // pred from h_{512+d} = pred_{d-1}
    float xin = (d == 0) ? ldf(src, (size_t)col * 4096 + 4088, isbf) : pr;
    if (hb == 0 && q == 0 && d > 0) {
      int oi = col * 96 + (d - 1);
      if (isbf) ((unsigned short*)outp)[oi] = f2bf(pr);
      else      ((float*)outp)[oi] = pr;
    }
    f32x4 hw;
#pragma unroll
    for (int r = 0; r < 4; ++r) {
      int m = q * 4 + r;
      float gi = acc[0][r] + xin * uDL[m]      + bDL[m];
      float gf = acc[1][r] + xin * uDL[16 + m] + bDL[16 + m];
      float gg = acc[2][r] + xin * uDL[32 + m] + bDL[32 + m];
      float go = acc[3][r] + xin * uDL[48 + m] + bDL[48 + m];
      cst[r] = sigm(gf) * cst[r] + sigm(gi) * tanh_(gg);
      hw[r] = sigm(go) * tanh_(cst[r]);
    }
    split_store3(wrW + sboff, hw);
    vm_drain();
    PUBLISH(nn + 1);
  }

  // ================= epilogue: pred_95 from h_608 (planes in HsA) =================
  if (hb == 0) {
    WAIT(608u);
    short8 hv[48];
    load_planes48(HsA + lboff, hv);
    float pd = 0.f;
#pragma unroll
    for (int kb = 0; kb < 16; ++kb)
#pragma unroll
      for (int j = 0; j < 8; ++j) {
        pd += WfcL[kb * 32 + q * 8 + j] *
              (bf2f(hv[kb * 3 + 0][j]) + bf2f(hv[kb * 3 + 1][j]) + bf2f(hv[kb * 3 + 2][j]));
      }
    pd += __shfl_xor(pd, 16);
    pd += __shfl_xor(pd, 32);
    if (q == 0) {
      float pr = sigm(pd + WfcL[512]);
      int oi = col * 96 + 95;
      if (isbf) ((unsigned short*)outp)[oi] = f2bf(pr);
      else      ((float*)outp)[oi] = pr;
    }
  }
#undef WAIT
#undef PUBLISH
}

// ---------- host ----------
extern "C" void kernel_launch(void* const* d_in, const int* in_sizes, int n_in,
                              void* d_out, int out_size, void* d_ws, size_t ws_size,
                              hipStream_t stream) {
  (void)in_sizes; (void)n_in; (void)out_size; (void)ws_size;
  char* ws = (char*)d_ws;
  int* flag = (int*)ws;                                   // @0
  unsigned* arr = (unsigned*)(ws + 128);                  // 8 groups x 609 slots x 128 B
  size_t off = 128 + (size_t)8 * NSLOT * FS * 4 + 128;    // 128 + 623616 + 128
  short* AEnc = (short*)(ws + off);           off += (size_t)2176 * 512 * 2;  // 2228224
  short* ADec = (short*)(ws + off);           off += (size_t)2048 * 512 * 2;  // 2097152
  unsigned short* XF = (unsigned short*)(ws + off); off += (size_t)524288 * 2; // 1048576
  char* HsA = ws + off; off += (size_t)128 * 3072;        // 393216: h planes ping
  char* HsB = ws + off; off += (size_t)128 * 3072;        // 393216: h planes pong
  float* bE   = (float*)(ws + off); off += 8192;
  float* uD   = (float*)(ws + off); off += 8192;
  float* bD   = (float*)(ws + off); off += 8192;
  float* WfcF = (float*)(ws + off); off += 2080;

  // inputs: 0 src, 1 Wih_e, 2 Whh_e, 3 bih_e, 4 bhh_e, 5 Wih_d, 6 Whh_d,
  //         7 bih_d, 8 bhh_d, 9 Wp, 10 bp, 11 Wfc, 12 bfc
  k_probe<<<dim3(1), dim3(256), 0, stream>>>((const unsigned int*)d_in[0], flag);
  k_prep_frags<<<dim3(4224), dim3(64), 0, stream>>>(
      d_in[2], d_in[6], d_in[1], AEnc, ADec, flag);
  k_prep_xf<<<dim3(2048), dim3(256), 0, stream>>>(d_in[0], XF, flag);
  k_prep_small<<<dim3(16), dim3(256), 0, stream>>>(
      d_in[3], d_in[4], d_in[7], d_in[8], d_in[5], d_in[9], d_in[10],
      d_in[11], d_in[12], bE, uD, bD, WfcF, arr, flag);
  k_rnn<<<dim3(64), dim3(256), 0, stream>>>(
      AEnc, ADec, XF, bE, uD, bD, WfcF, HsA, HsB, d_out, flag, arr, d_in[0]);
}

// Round 4
// 5142.751 us; speedup vs baseline: 1.0822x; 1.0822x over previous
//
#include <hip/hip_runtime.h>
#include <hip/hip_bf16.h>

// ForecastNetSimple: B=128, T=512, I=8, H=512, W=96
// Round 13: r10 verbatim + DVFS heater blocks.
//  r9-r12 post-mortem: step time is pinned at ~8.3us regardless of compute
//  (VALU 10->3.8%) or sync mechanics (scope, flag aggregation). Cycle model
//  of the exchange chain says ~2us @2.4GHz. Theory: 64/256 CUs active, >80%
//  stalled -> power governor drops clocks ~2.5x -> every latency inflates in
//  wall time. Test: blocks 64..255 are HEATERS -- dependent-FMA spin on the
//  idle CUs (1 block/CU via the same 138KB LDS footprint), polling a done
//  flag every ~8k cycles. Heaters write nothing -> zero correctness risk.
//  Blocks 0..63 are byte-identical r10 RNN blocks (proven absmax 0.0,
//  5068us); blocks 0/1 set done after their epilogue.
// 64 RNN blocks x 256 threads, 1 block/CU; per-wave flags, no __syncthreads
// in the 608-step loop.

typedef __attribute__((ext_vector_type(8))) short short8;
typedef __attribute__((ext_vector_type(4))) float f32x4;
typedef __attribute__((ext_vector_type(2))) unsigned int u32x2;

#define FS 32  // dwords between flags (128 B)
#define DONE_IDX 8192  // dword index of heater done-flag line in arr

// ---------- dtype helpers ----------
__device__ __forceinline__ float ldf(const void* p, size_t i, int isbf) {
  if (isbf) return __uint_as_float((unsigned)((const unsigned short*)p)[i] << 16);
  return ((const float*)p)[i];
}
__device__ __forceinline__ unsigned short f2bf(float x) {  // RNE
  unsigned u = __float_as_uint(x);
  return (unsigned short)((u + 0x7fff + ((u >> 16) & 1)) >> 16);
}
__device__ __forceinline__ unsigned short ldbf(const void* p, size_t i, int isbf) {
  if (isbf) return ((const unsigned short*)p)[i];
  return f2bf(((const float*)p)[i]);
}
__device__ __forceinline__ float bf2f(short s) {
  return __uint_as_float((unsigned)(unsigned short)s << 16);
}

// ---------- coherent access ----------
__device__ __forceinline__ unsigned ld_flag(const unsigned* p) {
  return __hip_atomic_load(p, __ATOMIC_RELAXED, __HIP_MEMORY_SCOPE_AGENT);
}
__device__ __forceinline__ void st_flag(unsigned* p, unsigned v) {
  __hip_atomic_store(p, v, __ATOMIC_RELAXED, __HIP_MEMORY_SCOPE_AGENT);
}
__device__ __forceinline__ void st_cx2(void* p, u32x2 v) {
  asm volatile("global_store_dwordx2 %0, %1, off sc0 sc1" :: "v"(p), "v"(v) : "memory");
}
__device__ __forceinline__ void vm_drain() {
  asm volatile("s_waitcnt vmcnt(0)" ::: "memory");
}

// ---- batch plane load: 48 x b128 coherent loads + internal drain (contract-safe:
//      no in-flight dest register is ever visible to the compiler) ----
// layout: base = Hs + col*3072 + q*16 ; fragment i = kb*3+plane at byte i*64
__device__ __forceinline__ void load_planes48(const char* p, short8 hv[48]) {
  asm volatile(
    "global_load_dwordx4 %0, %48, off sc0 sc1\n\t"
    "global_load_dwordx4 %1, %48, off offset:64 sc0 sc1\n\t"
    "global_load_dwordx4 %2, %48, off offset:128 sc0 sc1\n\t"
    "global_load_dwordx4 %3, %48, off offset:192 sc0 sc1\n\t"
    "global_load_dwordx4 %4, %48, off offset:256 sc0 sc1\n\t"
    "global_load_dwordx4 %5, %48, off offset:320 sc0 sc1\n\t"
    "global_load_dwordx4 %6, %48, off offset:384 sc0 sc1\n\t"
    "global_load_dwordx4 %7, %48, off offset:448 sc0 sc1\n\t"
    "global_load_dwordx4 %8, %48, off offset:512 sc0 sc1\n\t"
    "global_load_dwordx4 %9, %48, off offset:576 sc0 sc1\n\t"
    "global_load_dwordx4 %10, %48, off offset:640 sc0 sc1\n\t"
    "global_load_dwordx4 %11, %48, off offset:704 sc0 sc1\n\t"
    "global_load_dwordx4 %12, %48, off offset:768 sc0 sc1\n\t"
    "global_load_dwordx4 %13, %48, off offset:832 sc0 sc1\n\t"
    "global_load_dwordx4 %14, %48, off offset:896 sc0 sc1\n\t"
    "global_load_dwordx4 %15, %48, off offset:960 sc0 sc1\n\t"
    "global_load_dwordx4 %16, %48, off offset:1024 sc0 sc1\n\t"
    "global_load_dwordx4 %17, %48, off offset:1088 sc0 sc1\n\t"
    "global_load_dwordx4 %18, %48, off offset:1152 sc0 sc1\n\t"
    "global_load_dwordx4 %19, %48, off offset:1216 sc0 sc1\n\t"
    "global_load_dwordx4 %20, %48, off offset:1280 sc0 sc1\n\t"
    "global_load_dwordx4 %21, %48, off offset:1344 sc0 sc1\n\t"
    "global_load_dwordx4 %22, %48, off offset:1408 sc0 sc1\n\t"
    "global_load_dwordx4 %23, %48, off offset:1472 sc0 sc1\n\t"
    "global_load_dwordx4 %24, %48, off offset:1536 sc0 sc1\n\t"
    "global_load_dwordx4 %25, %48, off offset:1600 sc0 sc1\n\t"
    "global_load_dwordx4 %26, %48, off offset:1664 sc0 sc1\n\t"
    "global_load_dwordx4 %27, %48, off offset:1728 sc0 sc1\n\t"
    "global_load_dwordx4 %28, %48, off offset:1792 sc0 sc1\n\t"
    "global_load_dwordx4 %29, %48, off offset:1856 sc0 sc1\n\t"
    "global_load_dwordx4 %30, %48, off offset:1920 sc0 sc1\n\t"
    "global_load_dwordx4 %31, %48, off offset:1984 sc0 sc1\n\t"
    "global_load_dwordx4 %32, %48, off offset:2048 sc0 sc1\n\t"
    "global_load_dwordx4 %33, %48, off offset:2112 sc0 sc1\n\t"
    "global_load_dwordx4 %34, %48, off offset:2176 sc0 sc1\n\t"
    "global_load_dwordx4 %35, %48, off offset:2240 sc0 sc1\n\t"
    "global_load_dwordx4 %36, %48, off offset:2304 sc0 sc1\n\t"
    "global_load_dwordx4 %37, %48, off offset:2368 sc0 sc1\n\t"
    "global_load_dwordx4 %38, %48, off offset:2432 sc0 sc1\n\t"
    "global_load_dwordx4 %39, %48, off offset:2496 sc0 sc1\n\t"
    "global_load_dwordx4 %40, %48, off offset:2560 sc0 sc1\n\t"
    "global_load_dwordx4 %41, %48, off offset:2624 sc0 sc1\n\t"
    "global_load_dwordx4 %42, %48, off offset:2688 sc0 sc1\n\t"
    "global_load_dwordx4 %43, %48, off offset:2752 sc0 sc1\n\t"
    "global_load_dwordx4 %44, %48, off offset:2816 sc0 sc1\n\t"
    "global_load_dwordx4 %45, %48, off offset:2880 sc0 sc1\n\t"
    "global_load_dwordx4 %46, %48, off offset:2944 sc0 sc1\n\t"
    "global_load_dwordx4 %47, %48, off offset:3008 sc0 sc1\n\t"
    "s_waitcnt vmcnt(0)"
    : "=&v"(hv[0]),  "=&v"(hv[1]),  "=&v"(hv[2]),  "=&v"(hv[3]),
      "=&v"(hv[4]),  "=&v"(hv[5]),  "=&v"(hv[6]),  "=&v"(hv[7]),
      "=&v"(hv[8]),  "=&v"(hv[9]),  "=&v"(hv[10]), "=&v"(hv[11]),
      "=&v"(hv[12]), "=&v"(hv[13]), "=&v"(hv[14]), "=&v"(hv[15]),
      "=&v"(hv[16]), "=&v"(hv[17]), "=&v"(hv[18]), "=&v"(hv[19]),
      "=&v"(hv[20]), "=&v"(hv[21]), "=&v"(hv[22]), "=&v"(hv[23]),
      "=&v"(hv[24]), "=&v"(hv[25]), "=&v"(hv[26]), "=&v"(hv[27]),
      "=&v"(hv[28]), "=&v"(hv[29]), "=&v"(hv[30]), "=&v"(hv[31]),
      "=&v"(hv[32]), "=&v"(hv[33]), "=&v"(hv[34]), "=&v"(hv[35]),
      "=&v"(hv[36]), "=&v"(hv[37]), "=&v"(hv[38]), "=&v"(hv[39]),
      "=&v"(hv[40]), "=&v"(hv[41]), "=&v"(hv[42]), "=&v"(hv[43]),
      "=&v"(hv[44]), "=&v"(hv[45]), "=&v"(hv[46]), "=&v"(hv[47])
    : "v"(p)
    : "memory");
}

// ---- producer: exact 3-way RNE split of 4 h values + coherent plane stores ----
// sb = Hs + col*3072 + (hb>>1)*192 + (hb&1)*32 + q*8 ; plane p at sb + p*64
__device__ __forceinline__ void split_store3(char* sb, const f32x4& hw) {
  unsigned pa[3][4];
#pragma unroll
  for (int r = 0; r < 4; ++r) {
    float x = hw[r];
    unsigned short a = f2bf(x);
    float r1 = x - bf2f((short)a);
    unsigned short bq = f2bf(r1);
    float r2 = r1 - bf2f((short)bq);
    pa[0][r] = a; pa[1][r] = bq; pa[2][r] = f2bf(r2);
  }
#pragma unroll
  for (int p3 = 0; p3 < 3; ++p3) {
    u32x2 v;
    v.x = pa[p3][0] | (pa[p3][1] << 16);
    v.y = pa[p3][2] | (pa[p3][3] << 16);
    st_cx2(sb + p3 * 64, v);
  }
}

// ---------- heater: dependent-FMA spin to hold clocks up; exits on done flag ----------
__device__ __forceinline__ void heater(const unsigned* done) {
  float a = 1.0000001f, b = 0.9999999f, c = 0.f, d = 1.f;
  for (;;) {
#pragma unroll 32
    for (int i = 0; i < 1024; ++i) {
      a = __builtin_fmaf(a, b, 1e-7f);
      c = __builtin_fmaf(c, b, a);
      d = __builtin_fmaf(d, a, b);
      b = __builtin_fmaf(b, d, -1e-7f);
    }
    asm volatile("" :: "v"(a), "v"(b), "v"(c), "v"(d));
    if (ld_flag(done)) break;
  }
}

// ---------- probe: bf16 vs fp32 input buffers ----------
__global__ void k_probe(const unsigned int* __restrict__ src_raw, int* __restrict__ flag) {
  __shared__ int cnt;
  if (threadIdx.x == 0) cnt = 0;
  __syncthreads();
  int c = 0;
  for (int i = threadIdx.x; i < 512; i += 256) {
    unsigned v = src_raw[i];
    float f = __uint_as_float((v & 0xffffu) << 16);
    float a = fabsf(f);
    if (a > 0.00390625f && a < 4.0f) c++;
  }
  atomicAdd(&cnt, c);
  __syncthreads();
  if (threadIdx.x == 0) *flag = (cnt > 256) ? 1 : 0;
}

// ---------- prepack A fragments ----------
__global__ void k_prep_frags(const void* __restrict__ Whh_e, const void* __restrict__ Whh_d,
                             const void* __restrict__ Wih_e,
                             short* __restrict__ AEnc, short* __restrict__ ADec,
                             const int* __restrict__ flag) {
  const int isbf = *flag;
  const int lane = threadIdx.x;            // 64 threads
  const int m = lane & 15, qd = lane >> 4;
  int bidp = blockIdx.x;
  if (bidp < 2176) {
    const int hb = bidp / 68, rem = bidp % 68, t = rem / 17, kb = rem % 17;
    const int row = t * 512 + hb * 16 + m;
    short v[8];
#pragma unroll
    for (int j = 0; j < 8; ++j) {
      if (kb < 16) {
        int k = kb * 32 + qd * 8 + j;
        v[j] = (short)ldbf(Whh_e, (size_t)row * 512 + k, isbf);
      } else {
        v[j] = (qd == 0) ? (short)ldbf(Wih_e, (size_t)row * 8 + j, isbf) : (short)0;
      }
    }
    short* dst = AEnc + ((size_t)bidp * 64 + lane) * 8;
#pragma unroll
    for (int j = 0; j < 8; ++j) dst[j] = v[j];
  } else {
    bidp -= 2176;
    const int hb = bidp / 64, rem = bidp % 64, t = rem / 16, kb = rem % 16;
    const int row = t * 512 + hb * 16 + m;
    short* dst = ADec + ((size_t)bidp * 64 + lane) * 8;
#pragma unroll
    for (int j = 0; j < 8; ++j) {
      int k = kb * 32 + qd * 8 + j;
      dst[j] = (short)ldbf(Whh_d, (size_t)row * 512 + k, isbf);
    }
  }
}

// ---------- prepack encoder x B-frags: XF[t][col][8] bf16 ----------
__global__ void k_prep_xf(const void* __restrict__ src, unsigned short* __restrict__ XF,
                          const int* __restrict__ flag) {
  const int isbf = *flag;
  int idx = blockIdx.x * 256 + threadIdx.x;        // < 524288
  int t = idx >> 10, rem = idx & 1023, col = rem >> 3, i = rem & 7;
  XF[idx] = ldbf(src, ((size_t)col * 512 + t) * 8 + i, isbf);
}

// ---------- small prep ----------
__global__ void k_prep_small(const void* __restrict__ bih_e, const void* __restrict__ bhh_e,
                             const void* __restrict__ bih_d, const void* __restrict__ bhh_d,
                             const void* __restrict__ Wih_d, const void* __restrict__ Wp,
                             const void* __restrict__ bp, const void* __restrict__ Wfc,
                             const void* __restrict__ bfc,
                             float* __restrict__ bE, float* __restrict__ uD,
                             float* __restrict__ bD, float* __restrict__ WfcF,
                             unsigned* __restrict__ arr, const int* __restrict__ flag) {
  const int isbf = *flag;
  const int b = blockIdx.x;
  if (b < 8) {
    int g = b * 256 + threadIdx.x;
    bE[g] = ldf(bih_e, g, isbf) + ldf(bhh_e, g, isbf);
    float u = 0.f, w0 = 0.f;
    for (int i = 0; i < 8; ++i) {
      float wv = ldf(Wih_d, (size_t)g * 8 + i, isbf);
      u  += wv * ldf(Wp, i, isbf);
      w0 += wv * ldf(bp, i, isbf);
    }
    uD[g] = u;
    bD[g] = ldf(bih_d, g, isbf) + ldf(bhh_d, g, isbf) + w0;
  } else if (b == 8) {
    for (int k = threadIdx.x; k < 513; k += 256)
      WfcF[k] = (k < 512) ? ldf(Wfc, k, isbf) : ldf(bfc, 0, isbf);
  } else {
    // 256 wave-flags + done line (+pad)
    for (int i = threadIdx.x; i < 256 * FS + 2 * FS; i += 256) arr[i] = 0u;
  }
}

// ---------- math ----------
__device__ __forceinline__ float sigm(float x) { return 1.0f / (1.0f + __expf(-x)); }
__device__ __forceinline__ float tanh_(float x) {
  float ax = fabsf(x);
  float e = __expf(-2.0f * ax);
  float t = (1.0f - e) / (1.0f + e);
  return copysignf(t, x);
}

// ---------- main persistent recurrent kernel (blocks 0..63) + heaters (64..255) ----------
__global__ __launch_bounds__(256, 1) void k_rnn(
    const short* __restrict__ AEnc, const short* __restrict__ ADec,
    const unsigned short* __restrict__ XF,
    const float* __restrict__ bE, const float* __restrict__ uD,
    const float* __restrict__ bD, const float* __restrict__ WfcF,
    char* __restrict__ HsA, char* __restrict__ HsB,
    void* __restrict__ outp, const int* __restrict__ flag,
    unsigned* __restrict__ arr, const void* __restrict__ src) {
  const int bid  = (int)blockIdx.x;       // 256 blocks: 0..63 RNN, 64..255 heaters
  if (bid >= 64) { heater(arr + DONE_IDX); return; }

  const int hb   = bid >> 1;              // produces h rows hb*16 .. +16
  const int half = bid & 1;
  const int tid  = (int)threadIdx.x;
  const int lane = tid & 63;
  const int w    = __builtin_amdgcn_readfirstlane(tid >> 6);  // col-tile 0..3
  const int n    = lane & 15, q = lane >> 4;
  const int col  = half * 64 + w * 16 + n;

  __shared__ short AeL[4 * 17 * 512];     // 69632 B
  __shared__ short AdL[4 * 16 * 512];     // 65536 B
  __shared__ float WfcL[520];
  __shared__ float bEL[64], uDL[64], bDL[64];

  // ---- one-time staging ----
  {
    const float4* s1 = (const float4*)(AEnc + (size_t)hb * 34816);
    float4* d1 = (float4*)AeL;
    for (int i = tid; i < 4352; i += 256) d1[i] = s1[i];
    const float4* s2 = (const float4*)(ADec + (size_t)hb * 32768);
    float4* d2 = (float4*)AdL;
    for (int i = tid; i < 4096; i += 256) d2[i] = s2[i];
    for (int k = tid; k < 513; k += 256) WfcL[k] = WfcF[k];
    if (tid < 64) {
      int t = tid >> 4, m = tid & 15;
      int g = t * 512 + hb * 16 + m;
      bEL[tid] = bE[g]; uDL[tid] = uD[g]; bDL[tid] = bD[g];
    }
  }
  const int isbf = *flag;
  // wave flag id = ((hb*2+half)*4 + w); producers: all hb', same (half,w)
  const unsigned* pf = arr + (size_t)((((lane & 31) * 2 + half) * 4 + w) * FS);
  unsigned* myflag = arr + (size_t)(((hb * 2 + half) * 4 + w) * FS);
  __syncthreads();   // LDS staging visible; last block-level sync

  // plane buffer byte offsets: layout [col][kb][plane][32] ushorts (3072 B/col)
  const int lboff = col * 3072 + q * 16;                                    // consumer
  const int sboff = col * 3072 + (hb >> 1) * 192 + (hb & 1) * 32 + q * 8;   // producer
  float cst[4] = {0.f, 0.f, 0.f, 0.f};

#define WAIT(nn)                                                              \
  do {                                                                        \
    unsigned _n = (unsigned)(nn);                                             \
    while (!__all((int)(ld_flag(pf) >= _n))) __builtin_amdgcn_s_sleep(1);     \
    asm volatile("" ::: "memory");                                            \
  } while (0)

  // ================= encoder: 512 steps =================
  for (int t = 0; t < 512; ++t) {
    char* wrW = (t & 1) ? HsA : HsB;             // h_{t+1} planes
    f32x4 acc[4] = {{0.f,0.f,0.f,0.f},{0.f,0.f,0.f,0.f},{0.f,0.f,0.f,0.f},{0.f,0.f,0.f,0.f}};
    short8 xb = short8{0,0,0,0,0,0,0,0};
    if (q == 0) xb = *(const short8*)((const short*)XF + ((size_t)t * 128 + col) * 8);

    if (t > 0) {
      const char* rdR = (t & 1) ? HsB : HsA;     // h_t planes
      WAIT(t);
      short8 hv[48];
      load_planes48(rdR + lboff, hv);            // 48 b128 loads + drain, in-asm
#pragma unroll
      for (int kb = 0; kb < 16; ++kb) {
#pragma unroll
        for (int tt = 0; tt < 4; ++tt) {
          short8 a = *(const short8*)(AeL + ((size_t)(tt * 17 + kb) * 64 + lane) * 8);
          acc[tt] = __builtin_amdgcn_mfma_f32_16x16x32_bf16(a, hv[kb * 3 + 0], acc[tt], 0, 0, 0);
          acc[tt] = __builtin_amdgcn_mfma_f32_16x16x32_bf16(a, hv[kb * 3 + 1], acc[tt], 0, 0, 0);
          acc[tt] = __builtin_amdgcn_mfma_f32_16x16x32_bf16(a, hv[kb * 3 + 2], acc[tt], 0, 0, 0);
        }
      }
    }
#pragma unroll
    for (int tt = 0; tt < 4; ++tt) {   // x-term K-block (last: r7 order)
      short8 a = *(const short8*)(AeL + ((size_t)(tt * 17 + 16) * 64 + lane) * 8);
      acc[tt] = __builtin_amdgcn_mfma_f32_16x16x32_bf16(a, xb, acc[tt], 0, 0, 0);
    }
    f32x4 hw;
#pragma unroll
    for (int r = 0; r < 4; ++r) {
      int m = q * 4 + r;
      float gi = acc[0][r] + bEL[m];
      float gf = acc[1][r] + bEL[16 + m];
      float gg = acc[2][r] + bEL[32 + m];
      float go = acc[3][r] + bEL[48 + m];
      cst[r] = sigm(gf) * cst[r] + sigm(gi) * tanh_(gg);
      hw[r] = sigm(go) * tanh_(cst[r]);
    }
    split_store3(wrW + sboff, hw);
    vm_drain();
    if (lane == 0) st_flag(myflag, (unsigned)(t + 1));
  }

  // ================= decoder: 96 steps =================
  for (int d = 0; d < 96; ++d) {
    const int nn = 512 + d;
    const char* rdR = (nn & 1) ? HsB : HsA;
    char* wrW = (nn & 1) ? HsA : HsB;
    f32x4 acc[4] = {{0.f,0.f,0.f,0.f},{0.f,0.f,0.f,0.f},{0.f,0.f,0.f,0.f},{0.f,0.f,0.f,0.f}};
    float pd = 0.f;
    WAIT(nn);
    short8 hv[48];
    load_planes48(rdR + lboff, hv);
#pragma unroll
    for (int kb = 0; kb < 16; ++kb) {
#pragma unroll
      for (int j = 0; j < 8; ++j) {               // Wfc dot: same term order as r7/r10
        pd += WfcL[kb * 32 + q * 8 + j] *
              (bf2f(hv[kb * 3 + 0][j]) + bf2f(hv[kb * 3 + 1][j]) + bf2f(hv[kb * 3 + 2][j]));
      }
#pragma unroll
      for (int tt = 0; tt < 4; ++tt) {
        short8 a = *(const short8*)(AdL + ((size_t)(tt * 16 + kb) * 64 + lane) * 8);
        acc[tt] = __builtin_amdgcn_mfma_f32_16x16x32_bf16(a, hv[kb * 3 + 0], acc[tt], 0, 0, 0);
        acc[tt] = __builtin_amdgcn_mfma_f32_16x16x32_bf16(a, hv[kb * 3 + 1], acc[tt], 0, 0, 0);
        acc[tt] = __builtin_amdgcn_mfma_f32_16x16x32_bf16(a, hv[kb * 3 + 2], acc[tt], 0, 0, 0);
      }
    }
    pd += __shfl_xor(pd, 16);
    pd += __shfl_xor(pd, 32);
    float pr = sigm(pd + WfcL[512]);             // pred from h_{512+d} = pred_{d-1}
    float xin = (d == 0) ? ldf(src, (size_t)col * 4096 + 4088, isbf) : pr;
    if (hb == 0 && q == 0 && d > 0) {
      int oi = col * 96 + (d - 1);
      if (isbf) ((unsigned short*)outp)[oi] = f2bf(pr);
      else      ((float*)outp)[oi] = pr;
    }
    f32x4 hw;
#pragma unroll
    for (int r = 0; r < 4; ++r) {
      int m = q * 4 + r;
      float gi = acc[0][r] + xin * uDL[m]      + bDL[m];
      float gf = acc[1][r] + xin * uDL[16 + m] + bDL[16 + m];
      float gg = acc[2][r] + xin * uDL[32 + m] + bDL[32 + m];
      float go = acc[3][r] + xin * uDL[48 + m] + bDL[48 + m];
      cst[r] = sigm(gf) * cst[r] + sigm(gi) * tanh_(gg);
      hw[r] = sigm(go) * tanh_(cst[r]);
    }
    split_store3(wrW + sboff, hw);
    vm_drain();
    if (lane == 0) st_flag(myflag, (unsigned)(nn + 1));
  }

  // ================= epilogue: pred_95 from h_608 (planes in HsA) =================
  if (hb == 0) {
    WAIT(608u);
    short8 hv[48];
    load_planes48(HsA + lboff, hv);
    float pd = 0.f;
#pragma unroll
    for (int kb = 0; kb < 16; ++kb)
#pragma unroll
      for (int j = 0; j < 8; ++j) {
        float b0 = bf2f(hv[kb * 3 + 0][j]), b1 = bf2f(hv[kb * 3 + 1][j]), b2 = bf2f(hv[kb * 3 + 2][j]);
        pd += WfcL[kb * 32 + q * 8 + j] * (b0 + b1 + b2);
      }
    pd += __shfl_xor(pd, 16);
    pd += __shfl_xor(pd, 32);
    if (q == 0) {
      float pr = sigm(pd + WfcL[512]);
      int oi = col * 96 + 95;
      if (isbf) ((unsigned short*)outp)[oi] = f2bf(pr);
      else      ((float*)outp)[oi] = pr;
    }
    // shut heaters down (blocks 0 and 1 finish last)
    if (tid == 0) st_flag(arr + DONE_IDX, 1u);
  }
#undef WAIT
}

// ---------- host ----------
extern "C" void kernel_launch(void* const* d_in, const int* in_sizes, int n_in,
                              void* d_out, int out_size, void* d_ws, size_t ws_size,
                              hipStream_t stream) {
  (void)in_sizes; (void)n_in; (void)out_size; (void)ws_size;
  char* ws = (char*)d_ws;
  int* flag = (int*)ws;                                   // @0
  unsigned* arr = (unsigned*)(ws + 128);                  // 256 wave-flags x 128 B + done line
  size_t off = 128 + 33280 + 128;                         // flags + done + pad
  short* AEnc = (short*)(ws + off);           off += (size_t)2176 * 512 * 2;  // 2228224
  short* ADec = (short*)(ws + off);           off += (size_t)2048 * 512 * 2;  // 2097152
  unsigned short* XF = (unsigned short*)(ws + off); off += (size_t)524288 * 2; // 1048576
  char* HsA = ws + off; off += (size_t)128 * 3072;        // 393216: h planes ping
  char* HsB = ws + off; off += (size_t)128 * 3072;        // 393216: h planes pong
  float* bE   = (float*)(ws + off); off += 8192;
  float* uD   = (float*)(ws + off); off += 8192;
  float* bD   = (float*)(ws + off); off += 8192;
  float* WfcF = (float*)(ws + off); off += 2080;

  // inputs: 0 src, 1 Wih_e, 2 Whh_e, 3 bih_e, 4 bhh_e, 5 Wih_d, 6 Whh_d,
  //         7 bih_d, 8 bhh_d, 9 Wp, 10 bp, 11 Wfc, 12 bfc
  k_probe<<<dim3(1), dim3(256), 0, stream>>>((const unsigned int*)d_in[0], flag);
  k_prep_frags<<<dim3(4224), dim3(64), 0, stream>>>(
      d_in[2], d_in[6], d_in[1], AEnc, ADec, flag);
  k_prep_xf<<<dim3(2048), dim3(256), 0, stream>>>(d_in[0], XF, flag);
  k_prep_small<<<dim3(16), dim3(256), 0, stream>>>(
      d_in[3], d_in[4], d_in[7], d_in[8], d_in[5], d_in[9], d_in[10],
      d_in[11], d_in[12], bE, uD, bD, WfcF, arr, flag);
  k_rnn<<<dim3(256), dim3(256), 0, stream>>>(
      AEnc, ADec, XF, bE, uD, bD, WfcF, HsA, HsB, d_out, flag, arr, d_in[0]);
}

// Round 5
// 3521.294 us; speedup vs baseline: 1.5806x; 1.4605x over previous
//
#include <hip/hip_runtime.h>
#include <hip/hip_bf16.h>

// ForecastNetSimple: B=128, T=512, I=8, H=512, W=96
// Round 14: r10 semantics, 256x64 geometry (1 wave per CU).
//  r13 refuted DVFS (heaters: VALU 23%, dur unchanged). Remaining model: the
//  consumer gather (48 loads x ~16 line-requests = 768 line-reqs/wave/step)
//  is issue-throughput-bound at the CU. r10 packed 4 waves/CU -> ~3072
//  line-reqs per CU per step (~2.5-5us serial at 2-4cyc/req). Fix: same 256
//  waves spread over 256 blocks x 64 threads = 1 wave/CU -> 768 reqs/CU.
//  No sc0 tricks, no XCC handshake (r11's two failure sources removed):
//  data stores/loads system scope (sc0 sc1), flags agent scope, per-wave
//  flags, s_sleep poll -- exactly r10's proven-correct protocol. Fragment
//  layout, MFMA order, pd term order byte-identical -> absmax 0.0.
//  Bonus: chain (half,w) producers are bids == const (mod 8) -> same-XCD
//  locality under round-robin dispatch (perf-only, no correctness reliance).

typedef __attribute__((ext_vector_type(8))) short short8;
typedef __attribute__((ext_vector_type(4))) float f32x4;
typedef __attribute__((ext_vector_type(2))) unsigned int u32x2;

#define FS 32  // dwords between flags (128 B)

// ---------- dtype helpers ----------
__device__ __forceinline__ float ldf(const void* p, size_t i, int isbf) {
  if (isbf) return __uint_as_float((unsigned)((const unsigned short*)p)[i] << 16);
  return ((const float*)p)[i];
}
__device__ __forceinline__ unsigned short f2bf(float x) {  // RNE
  unsigned u = __float_as_uint(x);
  return (unsigned short)((u + 0x7fff + ((u >> 16) & 1)) >> 16);
}
__device__ __forceinline__ unsigned short ldbf(const void* p, size_t i, int isbf) {
  if (isbf) return ((const unsigned short*)p)[i];
  return f2bf(((const float*)p)[i]);
}
__device__ __forceinline__ float bf2f(short s) {
  return __uint_as_float((unsigned)(unsigned short)s << 16);
}

// ---------- coherent access ----------
__device__ __forceinline__ unsigned ld_flag(const unsigned* p) {
  return __hip_atomic_load(p, __ATOMIC_RELAXED, __HIP_MEMORY_SCOPE_AGENT);
}
__device__ __forceinline__ void st_flag(unsigned* p, unsigned v) {
  __hip_atomic_store(p, v, __ATOMIC_RELAXED, __HIP_MEMORY_SCOPE_AGENT);
}
__device__ __forceinline__ void st_cx2(void* p, u32x2 v) {
  asm volatile("global_store_dwordx2 %0, %1, off sc0 sc1" :: "v"(p), "v"(v) : "memory");
}
__device__ __forceinline__ void vm_drain() {
  asm volatile("s_waitcnt vmcnt(0)" ::: "memory");
}

// ---- batch plane load: 48 x b128 coherent loads + internal drain (contract-safe:
//      no in-flight dest register is ever visible to the compiler) ----
// layout: base = Hs + col*3072 + q*16 ; fragment i = kb*3+plane at byte i*64
__device__ __forceinline__ void load_planes48(const char* p, short8 hv[48]) {
  asm volatile(
    "global_load_dwordx4 %0, %48, off sc0 sc1\n\t"
    "global_load_dwordx4 %1, %48, off offset:64 sc0 sc1\n\t"
    "global_load_dwordx4 %2, %48, off offset:128 sc0 sc1\n\t"
    "global_load_dwordx4 %3, %48, off offset:192 sc0 sc1\n\t"
    "global_load_dwordx4 %4, %48, off offset:256 sc0 sc1\n\t"
    "global_load_dwordx4 %5, %48, off offset:320 sc0 sc1\n\t"
    "global_load_dwordx4 %6, %48, off offset:384 sc0 sc1\n\t"
    "global_load_dwordx4 %7, %48, off offset:448 sc0 sc1\n\t"
    "global_load_dwordx4 %8, %48, off offset:512 sc0 sc1\n\t"
    "global_load_dwordx4 %9, %48, off offset:576 sc0 sc1\n\t"
    "global_load_dwordx4 %10, %48, off offset:640 sc0 sc1\n\t"
    "global_load_dwordx4 %11, %48, off offset:704 sc0 sc1\n\t"
    "global_load_dwordx4 %12, %48, off offset:768 sc0 sc1\n\t"
    "global_load_dwordx4 %13, %48, off offset:832 sc0 sc1\n\t"
    "global_load_dwordx4 %14, %48, off offset:896 sc0 sc1\n\t"
    "global_load_dwordx4 %15, %48, off offset:960 sc0 sc1\n\t"
    "global_load_dwordx4 %16, %48, off offset:1024 sc0 sc1\n\t"
    "global_load_dwordx4 %17, %48, off offset:1088 sc0 sc1\n\t"
    "global_load_dwordx4 %18, %48, off offset:1152 sc0 sc1\n\t"
    "global_load_dwordx4 %19, %48, off offset:1216 sc0 sc1\n\t"
    "global_load_dwordx4 %20, %48, off offset:1280 sc0 sc1\n\t"
    "global_load_dwordx4 %21, %48, off offset:1344 sc0 sc1\n\t"
    "global_load_dwordx4 %22, %48, off offset:1408 sc0 sc1\n\t"
    "global_load_dwordx4 %23, %48, off offset:1472 sc0 sc1\n\t"
    "global_load_dwordx4 %24, %48, off offset:1536 sc0 sc1\n\t"
    "global_load_dwordx4 %25, %48, off offset:1600 sc0 sc1\n\t"
    "global_load_dwordx4 %26, %48, off offset:1664 sc0 sc1\n\t"
    "global_load_dwordx4 %27, %48, off offset:1728 sc0 sc1\n\t"
    "global_load_dwordx4 %28, %48, off offset:1792 sc0 sc1\n\t"
    "global_load_dwordx4 %29, %48, off offset:1856 sc0 sc1\n\t"
    "global_load_dwordx4 %30, %48, off offset:1920 sc0 sc1\n\t"
    "global_load_dwordx4 %31, %48, off offset:1984 sc0 sc1\n\t"
    "global_load_dwordx4 %32, %48, off offset:2048 sc0 sc1\n\t"
    "global_load_dwordx4 %33, %48, off offset:2112 sc0 sc1\n\t"
    "global_load_dwordx4 %34, %48, off offset:2176 sc0 sc1\n\t"
    "global_load_dwordx4 %35, %48, off offset:2240 sc0 sc1\n\t"
    "global_load_dwordx4 %36, %48, off offset:2304 sc0 sc1\n\t"
    "global_load_dwordx4 %37, %48, off offset:2368 sc0 sc1\n\t"
    "global_load_dwordx4 %38, %48, off offset:2432 sc0 sc1\n\t"
    "global_load_dwordx4 %39, %48, off offset:2496 sc0 sc1\n\t"
    "global_load_dwordx4 %40, %48, off offset:2560 sc0 sc1\n\t"
    "global_load_dwordx4 %41, %48, off offset:2624 sc0 sc1\n\t"
    "global_load_dwordx4 %42, %48, off offset:2688 sc0 sc1\n\t"
    "global_load_dwordx4 %43, %48, off offset:2752 sc0 sc1\n\t"
    "global_load_dwordx4 %44, %48, off offset:2816 sc0 sc1\n\t"
    "global_load_dwordx4 %45, %48, off offset:2880 sc0 sc1\n\t"
    "global_load_dwordx4 %46, %48, off offset:2944 sc0 sc1\n\t"
    "global_load_dwordx4 %47, %48, off offset:3008 sc0 sc1\n\t"
    "s_waitcnt vmcnt(0)"
    : "=&v"(hv[0]),  "=&v"(hv[1]),  "=&v"(hv[2]),  "=&v"(hv[3]),
      "=&v"(hv[4]),  "=&v"(hv[5]),  "=&v"(hv[6]),  "=&v"(hv[7]),
      "=&v"(hv[8]),  "=&v"(hv[9]),  "=&v"(hv[10]), "=&v"(hv[11]),
      "=&v"(hv[12]), "=&v"(hv[13]), "=&v"(hv[14]), "=&v"(hv[15]),
      "=&v"(hv[16]), "=&v"(hv[17]), "=&v"(hv[18]), "=&v"(hv[19]),
      "=&v"(hv[20]), "=&v"(hv[21]), "=&v"(hv[22]), "=&v"(hv[23]),
      "=&v"(hv[24]), "=&v"(hv[25]), "=&v"(hv[26]), "=&v"(hv[27]),
      "=&v"(hv[28]), "=&v"(hv[29]), "=&v"(hv[30]), "=&v"(hv[31]),
      "=&v"(hv[32]), "=&v"(hv[33]), "=&v"(hv[34]), "=&v"(hv[35]),
      "=&v"(hv[36]), "=&v"(hv[37]), "=&v"(hv[38]), "=&v"(hv[39]),
      "=&v"(hv[40]), "=&v"(hv[41]), "=&v"(hv[42]), "=&v"(hv[43]),
      "=&v"(hv[44]), "=&v"(hv[45]), "=&v"(hv[46]), "=&v"(hv[47])
    : "v"(p)
    : "memory");
}

// ---- producer: exact 3-way RNE split of 4 h values + coherent plane stores ----
// sb = Hs + col*3072 + (hb>>1)*192 + (hb&1)*32 + q*8 ; plane p at sb + p*64
__device__ __forceinline__ void split_store3(char* sb, const f32x4& hw) {
  unsigned pa[3][4];
#pragma unroll
  for (int r = 0; r < 4; ++r) {
    float x = hw[r];
    unsigned short a = f2bf(x);
    float r1 = x - bf2f((short)a);
    unsigned short bq = f2bf(r1);
    float r2 = r1 - bf2f((short)bq);
    pa[0][r] = a; pa[1][r] = bq; pa[2][r] = f2bf(r2);
  }
#pragma unroll
  for (int p3 = 0; p3 < 3; ++p3) {
    u32x2 v;
    v.x = pa[p3][0] | (pa[p3][1] << 16);
    v.y = pa[p3][2] | (pa[p3][3] << 16);
    st_cx2(sb + p3 * 64, v);
  }
}

// ---------- probe: bf16 vs fp32 input buffers ----------
__global__ void k_probe(const unsigned int* __restrict__ src_raw, int* __restrict__ flag) {
  __shared__ int cnt;
  if (threadIdx.x == 0) cnt = 0;
  __syncthreads();
  int c = 0;
  for (int i = threadIdx.x; i < 512; i += 256) {
    unsigned v = src_raw[i];
    float f = __uint_as_float((v & 0xffffu) << 16);
    float a = fabsf(f);
    if (a > 0.00390625f && a < 4.0f) c++;
  }
  atomicAdd(&cnt, c);
  __syncthreads();
  if (threadIdx.x == 0) *flag = (cnt > 256) ? 1 : 0;
}

// ---------- prepack A fragments ----------
__global__ void k_prep_frags(const void* __restrict__ Whh_e, const void* __restrict__ Whh_d,
                             const void* __restrict__ Wih_e,
                             short* __restrict__ AEnc, short* __restrict__ ADec,
                             const int* __restrict__ flag) {
  const int isbf = *flag;
  const int lane = threadIdx.x;            // 64 threads
  const int m = lane & 15, qd = lane >> 4;
  int bidp = blockIdx.x;
  if (bidp < 2176) {
    const int hb = bidp / 68, rem = bidp % 68, t = rem / 17, kb = rem % 17;
    const int row = t * 512 + hb * 16 + m;
    short v[8];
#pragma unroll
    for (int j = 0; j < 8; ++j) {
      if (kb < 16) {
        int k = kb * 32 + qd * 8 + j;
        v[j] = (short)ldbf(Whh_e, (size_t)row * 512 + k, isbf);
      } else {
        v[j] = (qd == 0) ? (short)ldbf(Wih_e, (size_t)row * 8 + j, isbf) : (short)0;
      }
    }
    short* dst = AEnc + ((size_t)bidp * 64 + lane) * 8;
#pragma unroll
    for (int j = 0; j < 8; ++j) dst[j] = v[j];
  } else {
    bidp -= 2176;
    const int hb = bidp / 64, rem = bidp % 64, t = rem / 16, kb = rem % 16;
    const int row = t * 512 + hb * 16 + m;
    short* dst = ADec + ((size_t)bidp * 64 + lane) * 8;
#pragma unroll
    for (int j = 0; j < 8; ++j) {
      int k = kb * 32 + qd * 8 + j;
      dst[j] = (short)ldbf(Whh_d, (size_t)row * 512 + k, isbf);
    }
  }
}

// ---------- prepack encoder x B-frags: XF[t][col][8] bf16 ----------
__global__ void k_prep_xf(const void* __restrict__ src, unsigned short* __restrict__ XF,
                          const int* __restrict__ flag) {
  const int isbf = *flag;
  int idx = blockIdx.x * 256 + threadIdx.x;        // < 524288
  int t = idx >> 10, rem = idx & 1023, col = rem >> 3, i = rem & 7;
  XF[idx] = ldbf(src, ((size_t)col * 512 + t) * 8 + i, isbf);
}

// ---------- small prep ----------
__global__ void k_prep_small(const void* __restrict__ bih_e, const void* __restrict__ bhh_e,
                             const void* __restrict__ bih_d, const void* __restrict__ bhh_d,
                             const void* __restrict__ Wih_d, const void* __restrict__ Wp,
                             const void* __restrict__ bp, const void* __restrict__ Wfc,
                             const void* __restrict__ bfc,
                             float* __restrict__ bE, float* __restrict__ uD,
                             float* __restrict__ bD, float* __restrict__ WfcF,
                             unsigned* __restrict__ arr, const int* __restrict__ flag) {
  const int isbf = *flag;
  const int b = blockIdx.x;
  if (b < 8) {
    int g = b * 256 + threadIdx.x;
    bE[g] = ldf(bih_e, g, isbf) + ldf(bhh_e, g, isbf);
    float u = 0.f, w0 = 0.f;
    for (int i = 0; i < 8; ++i) {
      float wv = ldf(Wih_d, (size_t)g * 8 + i, isbf);
      u  += wv * ldf(Wp, i, isbf);
      w0 += wv * ldf(bp, i, isbf);
    }
    uD[g] = u;
    bD[g] = ldf(bih_d, g, isbf) + ldf(bhh_d, g, isbf) + w0;
  } else if (b == 8) {
    for (int k = threadIdx.x; k < 513; k += 256)
      WfcF[k] = (k < 512) ? ldf(Wfc, k, isbf) : ldf(bfc, 0, isbf);
  } else {
    // 256 block-flags (+pad)
    for (int i = threadIdx.x; i < 256 * FS + 2 * FS; i += 256) arr[i] = 0u;
  }
}

// ---------- math ----------
__device__ __forceinline__ float sigm(float x) { return 1.0f / (1.0f + __expf(-x)); }
__device__ __forceinline__ float tanh_(float x) {
  float ax = fabsf(x);
  float e = __expf(-2.0f * ax);
  float t = (1.0f - e) / (1.0f + e);
  return copysignf(t, x);
}

// ---------- main persistent recurrent kernel: 256 blocks x 64 threads ----------
__global__ __launch_bounds__(64, 1) void k_rnn(
    const short* __restrict__ AEnc, const short* __restrict__ ADec,
    const unsigned short* __restrict__ XF,
    const float* __restrict__ bE, const float* __restrict__ uD,
    const float* __restrict__ bD, const float* __restrict__ WfcF,
    char* __restrict__ HsA, char* __restrict__ HsB,
    void* __restrict__ outp, const int* __restrict__ flag,
    unsigned* __restrict__ arr, const void* __restrict__ src) {
  const int bid  = (int)blockIdx.x;       // 256 blocks, 1 wave each
  const int hb   = bid >> 3;              // produces h rows hb*16 .. +16
  const int half = (bid >> 2) & 1;
  const int w    = bid & 3;               // col-tile 0..3
  const int lane = (int)threadIdx.x;      // 64
  const int n    = lane & 15, q = lane >> 4;
  const int col  = half * 64 + w * 16 + n;

  __shared__ short AeL[4 * 17 * 512];     // 69632 B
  __shared__ short AdL[4 * 16 * 512];     // 65536 B
  __shared__ float WfcL[520];
  __shared__ float bEL[64], uDL[64], bDL[64];

  // ---- one-time staging (single wave) ----
  {
    const float4* s1 = (const float4*)(AEnc + (size_t)hb * 34816);
    float4* d1 = (float4*)AeL;
    for (int i = lane; i < 4352; i += 64) d1[i] = s1[i];
    const float4* s2 = (const float4*)(ADec + (size_t)hb * 32768);
    float4* d2 = (float4*)AdL;
    for (int i = lane; i < 4096; i += 64) d2[i] = s2[i];
    for (int k = lane; k < 513; k += 64) WfcL[k] = WfcF[k];
    {
      int t = lane >> 4, m = lane & 15;
      int g = t * 512 + hb * 16 + m;
      bEL[lane] = bE[g]; uDL[lane] = uD[g]; bDL[lane] = bD[g];
    }
  }
  const int isbf = *flag;
  // flag id = hb*8 + half*4 + w; producers for my chain: all hb', same (half,w)
  const unsigned* pf = arr + (size_t)(((lane & 31) * 8 + half * 4 + w) * FS);
  unsigned* myflag = arr + (size_t)((hb * 8 + half * 4 + w) * FS);
  __syncthreads();   // LDS staging visible (single wave; cheap)

  // plane buffer byte offsets: layout [col][kb][plane][32] ushorts (3072 B/col)
  const int lboff = col * 3072 + q * 16;                                    // consumer
  const int sboff = col * 3072 + (hb >> 1) * 192 + (hb & 1) * 32 + q * 8;   // producer
  float cst[4] = {0.f, 0.f, 0.f, 0.f};

#define WAIT(nn)                                                              \
  do {                                                                        \
    unsigned _n = (unsigned)(nn);                                             \
    while (!__all((int)(ld_flag(pf) >= _n))) __builtin_amdgcn_s_sleep(1);     \
    asm volatile("" ::: "memory");                                            \
  } while (0)

  // ================= encoder: 512 steps =================
  for (int t = 0; t < 512; ++t) {
    char* wrW = (t & 1) ? HsA : HsB;             // h_{t+1} planes
    f32x4 acc[4] = {{0.f,0.f,0.f,0.f},{0.f,0.f,0.f,0.f},{0.f,0.f,0.f,0.f},{0.f,0.f,0.f,0.f}};
    short8 xb = short8{0,0,0,0,0,0,0,0};
    if (q == 0) xb = *(const short8*)((const short*)XF + ((size_t)t * 128 + col) * 8);

    if (t > 0) {
      const char* rdR = (t & 1) ? HsB : HsA;     // h_t planes
      WAIT(t);
      short8 hv[48];
      load_planes48(rdR + lboff, hv);            // 48 b128 loads + drain, in-asm
#pragma unroll
      for (int kb = 0; kb < 16; ++kb) {
#pragma unroll
        for (int tt = 0; tt < 4; ++tt) {
          short8 a = *(const short8*)(AeL + ((size_t)(tt * 17 + kb) * 64 + lane) * 8);
          acc[tt] = __builtin_amdgcn_mfma_f32_16x16x32_bf16(a, hv[kb * 3 + 0], acc[tt], 0, 0, 0);
          acc[tt] = __builtin_amdgcn_mfma_f32_16x16x32_bf16(a, hv[kb * 3 + 1], acc[tt], 0, 0, 0);
          acc[tt] = __builtin_amdgcn_mfma_f32_16x16x32_bf16(a, hv[kb * 3 + 2], acc[tt], 0, 0, 0);
        }
      }
    }
#pragma unroll
    for (int tt = 0; tt < 4; ++tt) {   // x-term K-block (last: r7 order)
      short8 a = *(const short8*)(AeL + ((size_t)(tt * 17 + 16) * 64 + lane) * 8);
      acc[tt] = __builtin_amdgcn_mfma_f32_16x16x32_bf16(a, xb, acc[tt], 0, 0, 0);
    }
    f32x4 hw;
#pragma unroll
    for (int r = 0; r < 4; ++r) {
      int m = q * 4 + r;
      float gi = acc[0][r] + bEL[m];
      float gf = acc[1][r] + bEL[16 + m];
      float gg = acc[2][r] + bEL[32 + m];
      float go = acc[3][r] + bEL[48 + m];
      cst[r] = sigm(gf) * cst[r] + sigm(gi) * tanh_(gg);
      hw[r] = sigm(go) * tanh_(cst[r]);
    }
    split_store3(wrW + sboff, hw);
    vm_drain();
    if (lane == 0) st_flag(myflag, (unsigned)(t + 1));
  }

  // ================= decoder: 96 steps =================
  for (int d = 0; d < 96; ++d) {
    const int nn = 512 + d;
    const char* rdR = (nn & 1) ? HsB : HsA;
    char* wrW = (nn & 1) ? HsA : HsB;
    f32x4 acc[4] = {{0.f,0.f,0.f,0.f},{0.f,0.f,0.f,0.f},{0.f,0.f,0.f,0.f},{0.f,0.f,0.f,0.f}};
    float pd = 0.f;
    WAIT(nn);
    short8 hv[48];
    load_planes48(rdR + lboff, hv);
#pragma unroll
    for (int kb = 0; kb < 16; ++kb) {
#pragma unroll
      for (int j = 0; j < 8; ++j) {               // Wfc dot: same term order as r7/r10
        pd += WfcL[kb * 32 + q * 8 + j] *
              (bf2f(hv[kb * 3 + 0][j]) + bf2f(hv[kb * 3 + 1][j]) + bf2f(hv[kb * 3 + 2][j]));
      }
#pragma unroll
      for (int tt = 0; tt < 4; ++tt) {
        short8 a = *(const short8*)(AdL + ((size_t)(tt * 16 + kb) * 64 + lane) * 8);
        acc[tt] = __builtin_amdgcn_mfma_f32_16x16x32_bf16(a, hv[kb * 3 + 0], acc[tt], 0, 0, 0);
        acc[tt] = __builtin_amdgcn_mfma_f32_16x16x32_bf16(a, hv[kb * 3 + 1], acc[tt], 0, 0, 0);
        acc[tt] = __builtin_amdgcn_mfma_f32_16x16x32_bf16(a, hv[kb * 3 + 2], acc[tt], 0, 0, 0);
      }
    }
    pd += __shfl_xor(pd, 16);
    pd += __shfl_xor(pd, 32);
    float pr = sigm(pd + WfcL[512]);             // pred from h_{512+d} = pred_{d-1}
    float xin = (d == 0) ? ldf(src, (size_t)col * 4096 + 4088, isbf) : pr;
    if (hb == 0 && q == 0 && d > 0) {
      int oi = col * 96 + (d - 1);
      if (isbf) ((unsigned short*)outp)[oi] = f2bf(pr);
      else      ((float*)outp)[oi] = pr;
    }
    f32x4 hw;
#pragma unroll
    for (int r = 0; r < 4; ++r) {
      int m = q * 4 + r;
      float gi = acc[0][r] + xin * uDL[m]      + bDL[m];
      float gf = acc[1][r] + xin * uDL[16 + m] + bDL[16 + m];
      float gg = acc[2][r] + xin * uDL[32 + m] + bDL[32 + m];
      float go = acc[3][r] + xin * uDL[48 + m] + bDL[48 + m];
      cst[r] = sigm(gf) * cst[r] + sigm(gi) * tanh_(gg);
      hw[r] = sigm(go) * tanh_(cst[r]);
    }
    split_store3(wrW + sboff, hw);
    vm_drain();
    if (lane == 0) st_flag(myflag, (unsigned)(nn + 1));
  }

  // ================= epilogue: pred_95 from h_608 (planes in HsA) =================
  if (hb == 0) {
    WAIT(608u);
    short8 hv[48];
    load_planes48(HsA + lboff, hv);
    float pd = 0.f;
#pragma unroll
    for (int kb = 0; kb < 16; ++kb)
#pragma unroll
      for (int j = 0; j < 8; ++j) {
        pd += WfcL[kb * 32 + q * 8 + j] *
              (bf2f(hv[kb * 3 + 0][j]) + bf2f(hv[kb * 3 + 1][j]) + bf2f(hv[kb * 3 + 2][j]));
      }
    pd += __shfl_xor(pd, 16);
    pd += __shfl_xor(pd, 32);
    if (q == 0) {
      float pr = sigm(pd + WfcL[512]);
      int oi = col * 96 + 95;
      if (isbf) ((unsigned short*)outp)[oi] = f2bf(pr);
      else      ((float*)outp)[oi] = pr;
    }
  }
#undef WAIT
}

// ---------- host ----------
extern "C" void kernel_launch(void* const* d_in, const int* in_sizes, int n_in,
                              void* d_out, int out_size, void* d_ws, size_t ws_size,
                              hipStream_t stream) {
  (void)in_sizes; (void)n_in; (void)out_size; (void)ws_size;
  char* ws = (char*)d_ws;
  int* flag = (int*)ws;                                   // @0
  unsigned* arr = (unsigned*)(ws + 128);                  // 256 block-flags x 128 B (+pad)
  size_t off = 128 + 33280 + 128;
  short* AEnc = (short*)(ws + off);           off += (size_t)2176 * 512 * 2;  // 2228224
  short* ADec = (short*)(ws + off);           off += (size_t)2048 * 512 * 2;  // 2097152
  unsigned short* XF = (unsigned short*)(ws + off); off += (size_t)524288 * 2; // 1048576
  char* HsA = ws + off; off += (size_t)128 * 3072;        // 393216: h planes ping
  char* HsB = ws + off; off += (size_t)128 * 3072;        // 393216: h planes pong
  float* bE   = (float*)(ws + off); off += 8192;
  float* uD   = (float*)(ws + off); off += 8192;
  float* bD   = (float*)(ws + off); off += 8192;
  float* WfcF = (float*)(ws + off); off += 2080;

  // inputs: 0 src, 1 Wih_e, 2 Whh_e, 3 bih_e, 4 bhh_e, 5 Wih_d, 6 Whh_d,
  //         7 bih_d, 8 bhh_d, 9 Wp, 10 bp, 11 Wfc, 12 bfc
  k_probe<<<dim3(1), dim3(256), 0, stream>>>((const unsigned int*)d_in[0], flag);
  k_prep_frags<<<dim3(4224), dim3(64), 0, stream>>>(
      d_in[2], d_in[6], d_in[1], AEnc, ADec, flag);
  k_prep_xf<<<dim3(2048), dim3(256), 0, stream>>>(d_in[0], XF, flag);
  k_prep_small<<<dim3(16), dim3(256), 0, stream>>>(
      d_in[3], d_in[4], d_in[7], d_in[8], d_in[5], d_in[9], d_in[10],
      d_in[11], d_in[12], bE, uD, bD, WfcF, arr, flag);
  k_rnn<<<dim3(256), dim3(64), 0, stream>>>(
      AEnc, ADec, XF, bE, uD, bD, WfcF, HsA, HsB, d_out, flag, arr, d_in[0]);
}

// Round 7
// 3496.220 us; speedup vs baseline: 1.5919x; 1.0072x over previous
//
#include <hip/hip_runtime.h>
#include <hip/hip_bf16.h>

// ForecastNetSimple: B=128, T=512, I=8, H=512, W=96
// Round 16: r14 (proven 3521us, absmax 0.0) + packed per-chain flag line.
//  r15 post-mortem: both opaque failures (r11, r15) contained the XCC-ID
//  handshake + sc0-only scope path; sc0-only is below the needed coherence
//  scope (XCD spans 4 SEs) -> WAIT can deadlock. Retired for good. System
//  scope (sc0 sc1) everywhere, no handshake.
//  r14 budget gap (~2.2us explainable vs 5.8us measured) attributed to LLC
//  congestion from the poll sweep: each r14 poll iteration touched 32
//  distinct 128B flag lines x 256 waves continuously (~8k line-reqs/sweep),
//  inflating every exchange hop. Fix (the scope-independent good half of
//  r15): pack each chain's 32 flags into ONE 128B line -- lane l polls dword
//  l&31 of the same line -> 1 line-req per poll iteration per wave (32x poll
//  traffic cut). Producers store plain distinct dwords (no RMW).
//  Geometry, plane layout, load/store/MFMA/pd order byte-identical to r14
//  -> absmax 0.0.

typedef __attribute__((ext_vector_type(8))) short short8;
typedef __attribute__((ext_vector_type(4))) float f32x4;
typedef __attribute__((ext_vector_type(2))) unsigned int u32x2;

// ---------- dtype helpers ----------
__device__ __forceinline__ float ldf(const void* p, size_t i, int isbf) {
  if (isbf) return __uint_as_float((unsigned)((const unsigned short*)p)[i] << 16);
  return ((const float*)p)[i];
}
__device__ __forceinline__ unsigned short f2bf(float x) {  // RNE
  unsigned u = __float_as_uint(x);
  return (unsigned short)((u + 0x7fff + ((u >> 16) & 1)) >> 16);
}
__device__ __forceinline__ unsigned short ldbf(const void* p, size_t i, int isbf) {
  if (isbf) return ((const unsigned short*)p)[i];
  return f2bf(((const float*)p)[i]);
}
__device__ __forceinline__ float bf2f(short s) {
  return __uint_as_float((unsigned)(unsigned short)s << 16);
}

// ---------- coherent access (system scope everywhere) ----------
__device__ __forceinline__ unsigned ld_flag(const unsigned* p) {
  unsigned v;
  asm volatile("global_load_dword %0, %1, off sc0 sc1\n\ts_waitcnt vmcnt(0)"
               : "=&v"(v) : "v"(p) : "memory");
  return v;
}
__device__ __forceinline__ void st_flag(unsigned* p, unsigned v) {
  asm volatile("global_store_dword %0, %1, off sc0 sc1" :: "v"(p), "v"(v) : "memory");
}
__device__ __forceinline__ void st_cx2(void* p, u32x2 v) {
  asm volatile("global_store_dwordx2 %0, %1, off sc0 sc1" :: "v"(p), "v"(v) : "memory");
}
__device__ __forceinline__ void vm_drain() {
  asm volatile("s_waitcnt vmcnt(0)" ::: "memory");
}

// ---- batch plane load: 48 x b128 coherent loads + internal drain (contract-safe:
//      no in-flight dest register is ever visible to the compiler) ----
// layout: base = Hs + col*3072 + q*16 ; fragment i = kb*3+plane at byte i*64
__device__ __forceinline__ void load_planes48(const char* p, short8 hv[48]) {
  asm volatile(
    "global_load_dwordx4 %0, %48, off sc0 sc1\n\t"
    "global_load_dwordx4 %1, %48, off offset:64 sc0 sc1\n\t"
    "global_load_dwordx4 %2, %48, off offset:128 sc0 sc1\n\t"
    "global_load_dwordx4 %3, %48, off offset:192 sc0 sc1\n\t"
    "global_load_dwordx4 %4, %48, off offset:256 sc0 sc1\n\t"
    "global_load_dwordx4 %5, %48, off offset:320 sc0 sc1\n\t"
    "global_load_dwordx4 %6, %48, off offset:384 sc0 sc1\n\t"
    "global_load_dwordx4 %7, %48, off offset:448 sc0 sc1\n\t"
    "global_load_dwordx4 %8, %48, off offset:512 sc0 sc1\n\t"
    "global_load_dwordx4 %9, %48, off offset:576 sc0 sc1\n\t"
    "global_load_dwordx4 %10, %48, off offset:640 sc0 sc1\n\t"
    "global_load_dwordx4 %11, %48, off offset:704 sc0 sc1\n\t"
    "global_load_dwordx4 %12, %48, off offset:768 sc0 sc1\n\t"
    "global_load_dwordx4 %13, %48, off offset:832 sc0 sc1\n\t"
    "global_load_dwordx4 %14, %48, off offset:896 sc0 sc1\n\t"
    "global_load_dwordx4 %15, %48, off offset:960 sc0 sc1\n\t"
    "global_load_dwordx4 %16, %48, off offset:1024 sc0 sc1\n\t"
    "global_load_dwordx4 %17, %48, off offset:1088 sc0 sc1\n\t"
    "global_load_dwordx4 %18, %48, off offset:1152 sc0 sc1\n\t"
    "global_load_dwordx4 %19, %48, off offset:1216 sc0 sc1\n\t"
    "global_load_dwordx4 %20, %48, off offset:1280 sc0 sc1\n\t"
    "global_load_dwordx4 %21, %48, off offset:1344 sc0 sc1\n\t"
    "global_load_dwordx4 %22, %48, off offset:1408 sc0 sc1\n\t"
    "global_load_dwordx4 %23, %48, off offset:1472 sc0 sc1\n\t"
    "global_load_dwordx4 %24, %48, off offset:1536 sc0 sc1\n\t"
    "global_load_dwordx4 %25, %48, off offset:1600 sc0 sc1\n\t"
    "global_load_dwordx4 %26, %48, off offset:1664 sc0 sc1\n\t"
    "global_load_dwordx4 %27, %48, off offset:1728 sc0 sc1\n\t"
    "global_load_dwordx4 %28, %48, off offset:1792 sc0 sc1\n\t"
    "global_load_dwordx4 %29, %48, off offset:1856 sc0 sc1\n\t"
    "global_load_dwordx4 %30, %48, off offset:1920 sc0 sc1\n\t"
    "global_load_dwordx4 %31, %48, off offset:1984 sc0 sc1\n\t"
    "global_load_dwordx4 %32, %48, off offset:2048 sc0 sc1\n\t"
    "global_load_dwordx4 %33, %48, off offset:2112 sc0 sc1\n\t"
    "global_load_dwordx4 %34, %48, off offset:2176 sc0 sc1\n\t"
    "global_load_dwordx4 %35, %48, off offset:2240 sc0 sc1\n\t"
    "global_load_dwordx4 %36, %48, off offset:2304 sc0 sc1\n\t"
    "global_load_dwordx4 %37, %48, off offset:2368 sc0 sc1\n\t"
    "global_load_dwordx4 %38, %48, off offset:2432 sc0 sc1\n\t"
    "global_load_dwordx4 %39, %48, off offset:2496 sc0 sc1\n\t"
    "global_load_dwordx4 %40, %48, off offset:2560 sc0 sc1\n\t"
    "global_load_dwordx4 %41, %48, off offset:2624 sc0 sc1\n\t"
    "global_load_dwordx4 %42, %48, off offset:2688 sc0 sc1\n\t"
    "global_load_dwordx4 %43, %48, off offset:2752 sc0 sc1\n\t"
    "global_load_dwordx4 %44, %48, off offset:2816 sc0 sc1\n\t"
    "global_load_dwordx4 %45, %48, off offset:2880 sc0 sc1\n\t"
    "global_load_dwordx4 %46, %48, off offset:2944 sc0 sc1\n\t"
    "global_load_dwordx4 %47, %48, off offset:3008 sc0 sc1\n\t"
    "s_waitcnt vmcnt(0)"
    : "=&v"(hv[0]),  "=&v"(hv[1]),  "=&v"(hv[2]),  "=&v"(hv[3]),
      "=&v"(hv[4]),  "=&v"(hv[5]),  "=&v"(hv[6]),  "=&v"(hv[7]),
      "=&v"(hv[8]),  "=&v"(hv[9]),  "=&v"(hv[10]), "=&v"(hv[11]),
      "=&v"(hv[12]), "=&v"(hv[13]), "=&v"(hv[14]), "=&v"(hv[15]),
      "=&v"(hv[16]), "=&v"(hv[17]), "=&v"(hv[18]), "=&v"(hv[19]),
      "=&v"(hv[20]), "=&v"(hv[21]), "=&v"(hv[22]), "=&v"(hv[23]),
      "=&v"(hv[24]), "=&v"(hv[25]), "=&v"(hv[26]), "=&v"(hv[27]),
      "=&v"(hv[28]), "=&v"(hv[29]), "=&v"(hv[30]), "=&v"(hv[31]),
      "=&v"(hv[32]), "=&v"(hv[33]), "=&v"(hv[34]), "=&v"(hv[35]),
      "=&v"(hv[36]), "=&v"(hv[37]), "=&v"(hv[38]), "=&v"(hv[39]),
      "=&v"(hv[40]), "=&v"(hv[41]), "=&v"(hv[42]), "=&v"(hv[43]),
      "=&v"(hv[44]), "=&v"(hv[45]), "=&v"(hv[46]), "=&v"(hv[47])
    : "v"(p)
    : "memory");
}

// ---- producer: exact 3-way RNE split of 4 h values + coherent plane stores ----
// sb = Hs + col*3072 + (hb>>1)*192 + (hb&1)*32 + q*8 ; plane p at sb + p*64
__device__ __forceinline__ void split_store3(char* sb, const f32x4& hw) {
  unsigned pa[3][4];
#pragma unroll
  for (int r = 0; r < 4; ++r) {
    float x = hw[r];
    unsigned short a = f2bf(x);
    float r1 = x - bf2f((short)a);
    unsigned short bq = f2bf(r1);
    float r2 = r1 - bf2f((short)bq);
    pa[0][r] = a; pa[1][r] = bq; pa[2][r] = f2bf(r2);
  }
#pragma unroll
  for (int p3 = 0; p3 < 3; ++p3) {
    u32x2 v;
    v.x = pa[p3][0] | (pa[p3][1] << 16);
    v.y = pa[p3][2] | (pa[p3][3] << 16);
    st_cx2(sb + p3 * 64, v);
  }
}

// ---------- probe: bf16 vs fp32 input buffers ----------
__global__ void k_probe(const unsigned int* __restrict__ src_raw, int* __restrict__ flag) {
  __shared__ int cnt;
  if (threadIdx.x == 0) cnt = 0;
  __syncthreads();
  int c = 0;
  for (int i = threadIdx.x; i < 512; i += 256) {
    unsigned v = src_raw[i];
    float f = __uint_as_float((v & 0xffffu) << 16);
    float a = fabsf(f);
    if (a > 0.00390625f && a < 4.0f) c++;
  }
  atomicAdd(&cnt, c);
  __syncthreads();
  if (threadIdx.x == 0) *flag = (cnt > 256) ? 1 : 0;
}

// ---------- prepack A fragments ----------
__global__ void k_prep_frags(const void* __restrict__ Whh_e, const void* __restrict__ Whh_d,
                             const void* __restrict__ Wih_e,
                             short* __restrict__ AEnc, short* __restrict__ ADec,
                             const int* __restrict__ flag) {
  const int isbf = *flag;
  const int lane = threadIdx.x;            // 64 threads
  const int m = lane & 15, qd = lane >> 4;
  int bidp = blockIdx.x;
  if (bidp < 2176) {
    const int hb = bidp / 68, rem = bidp % 68, t = rem / 17, kb = rem % 17;
    const int row = t * 512 + hb * 16 + m;
    short v[8];
#pragma unroll
    for (int j = 0; j < 8; ++j) {
      if (kb < 16) {
        int k = kb * 32 + qd * 8 + j;
        v[j] = (short)ldbf(Whh_e, (size_t)row * 512 + k, isbf);
      } else {
        v[j] = (qd == 0) ? (short)ldbf(Wih_e, (size_t)row * 8 + j, isbf) : (short)0;
      }
    }
    short* dst = AEnc + ((size_t)bidp * 64 + lane) * 8;
#pragma unroll
    for (int j = 0; j < 8; ++j) dst[j] = v[j];
  } else {
    bidp -= 2176;
    const int hb = bidp / 64, rem = bidp % 64, t = rem / 16, kb = rem % 16;
    const int row = t * 512 + hb * 16 + m;
    short* dst = ADec + ((size_t)bidp * 64 + lane) * 8;
#pragma unroll
    for (int j = 0; j < 8; ++j) {
      int k = kb * 32 + qd * 8 + j;
      dst[j] = (short)ldbf(Whh_d, (size_t)row * 512 + k, isbf);
    }
  }
}

// ---------- prepack encoder x B-frags: XF[t][col][8] bf16 ----------
__global__ void k_prep_xf(const void* __restrict__ src, unsigned short* __restrict__ XF,
                          const int* __restrict__ flag) {
  const int isbf = *flag;
  int idx = blockIdx.x * 256 + threadIdx.x;        // < 524288
  int t = idx >> 10, rem = idx & 1023, col = rem >> 3, i = rem & 7;
  XF[idx] = ldbf(src, ((size_t)col * 512 + t) * 8 + i, isbf);
}

// ---------- small prep ----------
__global__ void k_prep_small(const void* __restrict__ bih_e, const void* __restrict__ bhh_e,
                             const void* __restrict__ bih_d, const void* __restrict__ bhh_d,
                             const void* __restrict__ Wih_d, const void* __restrict__ Wp,
                             const void* __restrict__ bp, const void* __restrict__ Wfc,
                             const void* __restrict__ bfc,
                             float* __restrict__ bE, float* __restrict__ uD,
                             float* __restrict__ bD, float* __restrict__ WfcF,
                             unsigned* __restrict__ arr, const int* __restrict__ flag) {
  const int isbf = *flag;
  const int b = blockIdx.x;
  if (b < 8) {
    int g = b * 256 + threadIdx.x;
    bE[g] = ldf(bih_e, g, isbf) + ldf(bhh_e, g, isbf);
    float u = 0.f, w0 = 0.f;
    for (int i = 0; i < 8; ++i) {
      float wv = ldf(Wih_d, (size_t)g * 8 + i, isbf);
      u  += wv * ldf(Wp, i, isbf);
      w0 += wv * ldf(bp, i, isbf);
    }
    uD[g] = u;
    bD[g] = ldf(bih_d, g, isbf) + ldf(bhh_d, g, isbf) + w0;
  } else if (b == 8) {
    for (int k = threadIdx.x; k < 513; k += 256)
      WfcF[k] = (k < 512) ? ldf(Wfc, k, isbf) : ldf(bfc, 0, isbf);
  } else if (b == 9) {
    // 8 chains x 32 packed flags (256 dw) + pad
    for (int i = threadIdx.x; i < 512; i += 256) arr[i] = 0u;
  }
}

// ---------- math ----------
__device__ __forceinline__ float sigm(float x) { return 1.0f / (1.0f + __expf(-x)); }
__device__ __forceinline__ float tanh_(float x) {
  float ax = fabsf(x);
  float e = __expf(-2.0f * ax);
  float t = (1.0f - e) / (1.0f + e);
  return copysignf(t, x);
}

// ---------- main persistent recurrent kernel: 256 blocks x 64 threads ----------
__global__ __launch_bounds__(64, 1) void k_rnn(
    const short* __restrict__ AEnc, const short* __restrict__ ADec,
    const unsigned short* __restrict__ XF,
    const float* __restrict__ bE, const float* __restrict__ uD,
    const float* __restrict__ bD, const float* __restrict__ WfcF,
    char* __restrict__ HsA, char* __restrict__ HsB,
    void* __restrict__ outp, const int* __restrict__ flag,
    unsigned* __restrict__ arr, const void* __restrict__ src) {
  const int bid   = (int)blockIdx.x;      // 256 blocks, 1 wave each
  const int hb    = bid >> 3;             // produces h rows hb*16 .. +16
  const int chain = bid & 7;              // = half*4 + w
  const int half  = (bid >> 2) & 1;
  const int w     = bid & 3;
  const int lane  = (int)threadIdx.x;     // 64
  const int n     = lane & 15, q = lane >> 4;
  const int col   = half * 64 + w * 16 + n;

  __shared__ short AeL[4 * 17 * 512];     // 69632 B
  __shared__ short AdL[4 * 16 * 512];     // 65536 B
  __shared__ float WfcL[520];
  __shared__ float bEL[64], uDL[64], bDL[64];

  // ---- one-time staging (single wave) ----
  {
    const float4* s1 = (const float4*)(AEnc + (size_t)hb * 34816);
    float4* d1 = (float4*)AeL;
    for (int i = lane; i < 4352; i += 64) d1[i] = s1[i];
    const float4* s2 = (const float4*)(ADec + (size_t)hb * 32768);
    float4* d2 = (float4*)AdL;
    for (int i = lane; i < 4096; i += 64) d2[i] = s2[i];
    for (int k = lane; k < 513; k += 64) WfcL[k] = WfcF[k];
    {
      int t = lane >> 4, m = lane & 15;
      int g = t * 512 + hb * 16 + m;
      bEL[lane] = bE[g]; uDL[lane] = uD[g]; bDL[lane] = bD[g];
    }
  }
  const int isbf = *flag;
  // packed flag line per chain (128 B): dword hb of line `chain`.
  // consumer: lane l polls dword (l&31) of its chain's line -> ONE line-req/poll.
  const unsigned* pf = arr + (size_t)(chain * 32 + (lane & 31));
  unsigned* myflag = arr + (size_t)(chain * 32 + hb);
  __syncthreads();   // LDS staging visible (single wave; cheap)

  // plane buffer byte offsets: layout [col][kb][plane][32] ushorts (3072 B/col)
  const int lboff = col * 3072 + q * 16;                                    // consumer
  const int sboff = col * 3072 + (hb >> 1) * 192 + (hb & 1) * 32 + q * 8;   // producer
  float cst[4] = {0.f, 0.f, 0.f, 0.f};

#define WAIT(nn)                                                              \
  do {                                                                        \
    unsigned _n = (unsigned)(nn);                                             \
    while (!__all((int)(ld_flag(pf) >= _n))) __builtin_amdgcn_s_sleep(1);     \
    asm volatile("" ::: "memory");                                            \
  } while (0)

  // ================= encoder: 512 steps =================
  for (int t = 0; t < 512; ++t) {
    char* wrW = (t & 1) ? HsA : HsB;             // h_{t+1} planes
    f32x4 acc[4] = {{0.f,0.f,0.f,0.f},{0.f,0.f,0.f,0.f},{0.f,0.f,0.f,0.f},{0.f,0.f,0.f,0.f}};
    short8 xb = short8{0,0,0,0,0,0,0,0};
    if (q == 0) xb = *(const short8*)((const short*)XF + ((size_t)t * 128 + col) * 8);

    if (t > 0) {
      const char* rdR = (t & 1) ? HsB : HsA;     // h_t planes
      WAIT(t);
      short8 hv[48];
      load_planes48(rdR + lboff, hv);            // 48 b128 loads + drain, in-asm
#pragma unroll
      for (int kb = 0; kb < 16; ++kb) {
#pragma unroll
        for (int tt = 0; tt < 4; ++tt) {
          short8 a = *(const short8*)(AeL + ((size_t)(tt * 17 + kb) * 64 + lane) * 8);
          acc[tt] = __builtin_amdgcn_mfma_f32_16x16x32_bf16(a, hv[kb * 3 + 0], acc[tt], 0, 0, 0);
          acc[tt] = __builtin_amdgcn_mfma_f32_16x16x32_bf16(a, hv[kb * 3 + 1], acc[tt], 0, 0, 0);
          acc[tt] = __builtin_amdgcn_mfma_f32_16x16x32_bf16(a, hv[kb * 3 + 2], acc[tt], 0, 0, 0);
        }
      }
    }
#pragma unroll
    for (int tt = 0; tt < 4; ++tt) {   // x-term K-block (last: r7 order)
      short8 a = *(const short8*)(AeL + ((size_t)(tt * 17 + 16) * 64 + lane) * 8);
      acc[tt] = __builtin_amdgcn_mfma_f32_16x16x32_bf16(a, xb, acc[tt], 0, 0, 0);
    }
    f32x4 hw;
#pragma unroll
    for (int r = 0; r < 4; ++r) {
      int m = q * 4 + r;
      float gi = acc[0][r] + bEL[m];
      float gf = acc[1][r] + bEL[16 + m];
      float gg = acc[2][r] + bEL[32 + m];
      float go = acc[3][r] + bEL[48 + m];
      cst[r] = sigm(gf) * cst[r] + sigm(gi) * tanh_(gg);
      hw[r] = sigm(go) * tanh_(cst[r]);
    }
    split_store3(wrW + sboff, hw);
    vm_drain();
    if (lane == 0) st_flag(myflag, (unsigned)(t + 1));
  }

  // ================= decoder: 96 steps =================
  for (int d = 0; d < 96; ++d) {
    const int nn = 512 + d;
    const char* rdR = (nn & 1) ? HsB : HsA;
    char* wrW = (nn & 1) ? HsA : HsB;
    f32x4 acc[4] = {{0.f,0.f,0.f,0.f},{0.f,0.f,0.f,0.f},{0.f,0.f,0.f,0.f},{0.f,0.f,0.f,0.f}};
    float pd = 0.f;
    WAIT(nn);
    short8 hv[48];
    load_planes48(rdR + lboff, hv);
#pragma unroll
    for (int kb = 0; kb < 16; ++kb) {
#pragma unroll
      for (int j = 0; j < 8; ++j) {               // Wfc dot: same term order as r7/r10
        pd += WfcL[kb * 32 + q * 8 + j] *
              (bf2f(hv[kb * 3 + 0][j]) + bf2f(hv[kb * 3 + 1][j]) + bf2f(hv[kb * 3 + 2][j]));
      }
#pragma unroll
      for (int tt = 0; tt < 4; ++tt) {
        short8 a = *(const short8*)(AdL + ((size_t)(tt * 16 + kb) * 64 + lane) * 8);
        acc[tt] = __builtin_amdgcn_mfma_f32_16x16x32_bf16(a, hv[kb * 3 + 0], acc[tt], 0, 0, 0);
        acc[tt] = __builtin_amdgcn_mfma_f32_16x16x32_bf16(a, hv[kb * 3 + 1], acc[tt], 0, 0, 0);
        acc[tt] = __builtin_amdgcn_mfma_f32_16x16x32_bf16(a, hv[kb * 3 + 2], acc[tt], 0, 0, 0);
      }
    }
    pd += __shfl_xor(pd, 16);
    pd += __shfl_xor(pd, 32);
    float pr = sigm(pd + WfcL[512]);             // pred from h_{512+d} = pred_{d-1}
    float xin = (d == 0) ? ldf(src, (size_t)col * 4096 + 4088, isbf) : pr;
    if (hb == 0 && q == 0 && d > 0) {
      int oi = col * 96 + (d - 1);
      if (isbf) ((unsigned short*)outp)[oi] = f2bf(pr);
      else      ((float*)outp)[oi] = pr;
    }
    f32x4 hw;
#pragma unroll
    for (int r = 0; r < 4; ++r) {
      int m = q * 4 + r;
      float gi = acc[0][r] + xin * uDL[m]      + bDL[m];
      float gf = acc[1][r] + xin * uDL[16 + m] + bDL[16 + m];
      float gg = acc[2][r] + xin * uDL[32 + m] + bDL[32 + m];
      float go = acc[3][r] + xin * uDL[48 + m] + bDL[48 + m];
      cst[r] = sigm(gf) * cst[r] + sigm(gi) * tanh_(gg);
      hw[r] = sigm(go) * tanh_(cst[r]);
    }
    split_store3(wrW + sboff, hw);
    vm_drain();
    if (lane == 0) st_flag(myflag, (unsigned)(nn + 1));
  }

  // ================= epilogue: pred_95 from h_608 (planes in HsA) =================
  if (hb == 0) {
    WAIT(608u);
    short8 hv[48];
    load_planes48(HsA + lboff, hv);
    float pd = 0.f;
#pragma unroll
    for (int kb = 0; kb < 16; ++kb)
#pragma unroll
      for (int j = 0; j < 8; ++j) {
        pd += WfcL[kb * 32 + q * 8 + j] *
              (bf2f(hv[kb * 3 + 0][j]) + bf2f(hv[kb * 3 + 1][j]) + bf2f(hv[kb * 3 + 2][j]));
      }
    pd += __shfl_xor(pd, 16);
    pd += __shfl_xor(pd, 32);
    if (q == 0) {
      float pr = sigm(pd + WfcL[512]);
      int oi = col * 96 + 95;
      if (isbf) ((unsigned short*)outp)[oi] = f2bf(pr);
      else      ((float*)outp)[oi] = pr;
    }
  }
#undef WAIT
}

// ---------- host ----------
extern "C" void kernel_launch(void* const* d_in, const int* in_sizes, int n_in,
                              void* d_out, int out_size, void* d_ws, size_t ws_size,
                              hipStream_t stream) {
  (void)in_sizes; (void)n_in; (void)out_size; (void)ws_size;
  char* ws = (char*)d_ws;
  int* flag = (int*)ws;                                   // @0
  unsigned* arr = (unsigned*)(ws + 128);                  // 8 chains x 32 packed flags (+pad)
  size_t off = 128 + 2048 + 128;
  short* AEnc = (short*)(ws + off);           off += (size_t)2176 * 512 * 2;  // 2228224
  short* ADec = (short*)(ws + off);           off += (size_t)2048 * 512 * 2;  // 2097152
  unsigned short* XF = (unsigned short*)(ws + off); off += (size_t)524288 * 2; // 1048576
  char* HsA = ws + off; off += (size_t)128 * 3072;        // 393216: h planes ping
  char* HsB = ws + off; off += (size_t)128 * 3072;        // 393216: h planes pong
  float* bE   = (float*)(ws + off); off += 8192;
  float* uD   = (float*)(ws + off); off += 8192;
  float* bD   = (float*)(ws + off); off += 8192;
  float* WfcF = (float*)(ws + off); off += 2080;

  // inputs: 0 src, 1 Wih_e, 2 Whh_e, 3 bih_e, 4 bhh_e, 5 Wih_d, 6 Whh_d,
  //         7 bih_d, 8 bhh_d, 9 Wp, 10 bp, 11 Wfc, 12 bfc
  k_probe<<<dim3(1), dim3(256), 0, stream>>>((const unsigned int*)d_in[0], flag);
  k_prep_frags<<<dim3(4224), dim3(64), 0, stream>>>(
      d_in[2], d_in[6], d_in[1], AEnc, ADec, flag);
  k_prep_xf<<<dim3(2048), dim3(256), 0, stream>>>(d_in[0], XF, flag);
  k_prep_small<<<dim3(10), dim3(256), 0, stream>>>(
      d_in[3], d_in[4], d_in[7], d_in[8], d_in[5], d_in[9], d_in[10],
      d_in[11], d_in[12], bE, uD, bD, WfcF, arr, flag);
  k_rnn<<<dim3(256), dim3(64), 0, stream>>>(
      AEnc, ADec, XF, bE, uD, bD, WfcF, HsA, HsB, d_out, flag, arr, d_in[0]);
}